// Round 1
// baseline (339.265 us; speedup 1.0000x reference)
//
#include <hip/hip_runtime.h>
#include <hip/hip_bf16.h>

typedef __attribute__((ext_vector_type(8))) short short8;
typedef __attribute__((ext_vector_type(4))) float f32x4;
typedef unsigned short u16;
typedef __attribute__((ext_vector_type(8))) unsigned short u16x8;

#define XN 16
#define XC 64
#define XH 256
#define XW 256
#define XO 64
#define CH_STRIDE (XH * XW)   // 65536

// Tile geometry for conv kernel
#define TILE_H 8
#define TILE_W 32
#define HALO_H 10
#define HALO_W 34
#define NPIX (HALO_H * HALO_W)   // 340

// ---------------------------------------------------------------------------
// Kernel 1: weight quantization. One block.
//  - mean(|w|) -> wm = clamp(mean, 1e-5); dqw = tern * wm, tern in {-1,0,1}
//  - writes wm to ws[0], and ternary weights (bf16 bits) pre-swizzled into the
//    MFMA A-fragment layout:
//      idx = (((t*4 + m)*2 + c)*64 + lane)*8 + j
//      holds tern[o = m*16 + (lane&15)][i = c*32 + (lane>>4)*8 + j][tap t]
// ---------------------------------------------------------------------------
__global__ __launch_bounds__(256) void wq_kernel(const float* __restrict__ w,
                                                 float* __restrict__ wm_out,
                                                 u16* __restrict__ wbuf) {
    __shared__ float red[4];
    __shared__ float wm_sh;
    const int tid = threadIdx.x;

    float s = 0.f;
    for (int i = tid; i < XO * XC * 9; i += 256) s += fabsf(w[i]);
    #pragma unroll
    for (int off = 32; off > 0; off >>= 1) s += __shfl_down(s, off, 64);
    if ((tid & 63) == 0) red[tid >> 6] = s;
    __syncthreads();
    if (tid == 0) {
        float tot = red[0] + red[1] + red[2] + red[3];
        float mean = tot / (float)(XO * XC * 9);
        float wm = fmaxf(mean, 1e-5f);
        wm_out[0] = wm;
        wm_sh = wm;
    }
    __syncthreads();
    const float wscale = 1.0f / wm_sh;

    for (int idx = tid; idx < XO * XC * 9; idx += 256) {
        const int j = idx & 7;
        const int l = (idx >> 3) & 63;
        const int c = (idx >> 9) & 1;
        const int m = (idx >> 10) & 3;
        const int t = idx >> 12;            // 0..8
        const int o = m * 16 + (l & 15);
        const int i = c * 32 + (l >> 4) * 8 + j;
        const int kh = t / 3, kw = t % 3;
        const float wv = w[((o * XC + i) * 3 + kh) * 3 + kw];
        const float tern = fminf(fmaxf(rintf(wv * wscale), -1.f), 1.f);
        wbuf[idx] = (u16)(__float_as_uint(tern) >> 16);   // exact in bf16
    }
}

// ---------------------------------------------------------------------------
// Kernel 2: fused activation-quant + 9-tap integer conv via bf16 MFMA.
// Block: 8x32 output pixels of one image. 4 waves.
// D[o][pixel] so output stores are coalesced (pixel = lane&15).
// ---------------------------------------------------------------------------
__global__ __launch_bounds__(256) void conv_kernel(const float* __restrict__ x,
                                                   const u16* __restrict__ wbuf,
                                                   const float* __restrict__ wm_ptr,
                                                   const float* __restrict__ bias,
                                                   float* __restrict__ out) {
    __shared__ __align__(16) u16 q_lds[NPIX * 64];   // 43,520 B, XOR-swizzled rows
    __shared__ float invs_lds[NPIX];
    __shared__ float bias_lds[XO];

    const int tid = threadIdx.x;
    const int bid = blockIdx.x;
    const int n   = bid >> 8;          // 256 blocks per image
    const int rem = bid & 255;
    const int h0  = (rem >> 3) << 3;   // 32 h-tiles of 8
    const int w0  = (rem & 7) << 5;    // 8 w-tiles of 32

    if (tid < XO) bias_lds[tid] = bias[tid];

    // ---- stage + per-pixel activation quant ----
    #pragma unroll 1
    for (int p = tid; p < NPIX; p += 256) {
        const int hr = p / HALO_W;
        const int cl = p - hr * HALO_W;
        const int gh = h0 + hr - 1;
        const int gw = w0 + cl - 1;
        const bool ok = (gh >= 0) & (gh < XH) & (gw >= 0) & (gw < XW);

        float vals[64];
        float amax = 0.f;
        if (ok) {
            const float* px = x + (size_t)n * (XC * CH_STRIDE) + (size_t)gh * XW + gw;
            #pragma unroll
            for (int c = 0; c < 64; ++c) {
                const float v = px[(size_t)c * CH_STRIDE];
                vals[c] = v;
                amax = fmaxf(amax, fabsf(v));
            }
        } else {
            #pragma unroll
            for (int c = 0; c < 64; ++c) vals[c] = 0.f;
        }
        const float am    = fmaxf(amax, 1e-5f);
        const float scale = 127.0f / am;
        invs_lds[p] = ok ? (1.0f / scale) : 0.0f;

        const int sw = (p & 7) << 3;   // XOR swizzle (ushort units)
        #pragma unroll
        for (int cb = 0; cb < 8; ++cb) {
            u16x8 pk;
            #pragma unroll
            for (int j = 0; j < 8; ++j) {
                const float q = fminf(fmaxf(rintf(vals[cb * 8 + j] * scale), -128.f), 127.f);
                pk[j] = (u16)(__float_as_uint(q) >> 16);   // exact int in bf16
            }
            *reinterpret_cast<u16x8*>(&q_lds[p * 64 + ((cb * 8) ^ sw)]) = pk;
        }
    }
    __syncthreads();

    const int lane = tid & 63;
    const int wv   = tid >> 6;     // wave 0..3 -> output rows {2wv, 2wv+1}
    const int l15  = lane & 15;
    const int lg   = lane >> 4;    // 0..3

    f32x4 acc[4][4];
    #pragma unroll
    for (int m = 0; m < 4; ++m)
        #pragma unroll
        for (int nt = 0; nt < 4; ++nt) acc[m][nt] = (f32x4){0.f, 0.f, 0.f, 0.f};

    const float wm = wm_ptr[0];

    #pragma unroll
    for (int t = 0; t < 9; ++t) {
        const int dh = t / 3, dw = t % 3;

        // A-fragments (ternary weights), pre-laid-out; L1/L2-resident
        short8 afr[4][2];
        #pragma unroll
        for (int m = 0; m < 4; ++m)
            #pragma unroll
            for (int c = 0; c < 2; ++c)
                afr[m][c] = *reinterpret_cast<const short8*>(
                    wbuf + ((((t * 4 + m) * 2 + c) * 64 + lane) * 8));

        #pragma unroll
        for (int nt = 0; nt < 4; ++nt) {
            const int rl  = 2 * wv + (nt >> 1);              // output row in tile
            const int pix = (rl + dh) * HALO_W + (nt & 1) * 16 + l15 + dw;
            const int sw  = (pix & 7) << 3;
            const u16* qp = &q_lds[pix * 64];
            const short8 b0 = *reinterpret_cast<const short8*>(qp + ((lg * 8) ^ sw));
            const short8 b1 = *reinterpret_cast<const short8*>(qp + ((32 + lg * 8) ^ sw));
            const float  iv = invs_lds[pix];
            #pragma unroll
            for (int m = 0; m < 4; ++m) {
                f32x4 tap = (f32x4){0.f, 0.f, 0.f, 0.f};
                tap = __builtin_amdgcn_mfma_f32_16x16x32_bf16(afr[m][0], b0, tap, 0, 0, 0);
                tap = __builtin_amdgcn_mfma_f32_16x16x32_bf16(afr[m][1], b1, tap, 0, 0, 0);
                acc[m][nt] += tap * iv;
            }
        }
    }

    // ---- epilogue: out = wm * acc + bias, coalesced 64B-per-lane-group ----
    #pragma unroll
    for (int m = 0; m < 4; ++m) {
        #pragma unroll
        for (int nt = 0; nt < 4; ++nt) {
            const int rl = 2 * wv + (nt >> 1);
            const int gh = h0 + rl;
            const int gw = w0 + (nt & 1) * 16 + l15;
            #pragma unroll
            for (int r = 0; r < 4; ++r) {
                const int o = m * 16 + lg * 4 + r;
                const float v = wm * acc[m][nt][r] + bias_lds[o];
                out[(((size_t)n * XO + o) * XH + gh) * XW + gw] = v;
            }
        }
    }
}

extern "C" void kernel_launch(void* const* d_in, const int* in_sizes, int n_in,
                              void* d_out, int out_size, void* d_ws, size_t ws_size,
                              hipStream_t stream) {
    const float* x    = (const float*)d_in[0];
    const float* w    = (const float*)d_in[1];
    const float* bias = (const float*)d_in[2];
    float* out = (float*)d_out;

    float* wsf = (float*)d_ws;
    u16*   wbuf = (u16*)((char*)d_ws + 64);   // 73,728 B of ternary bf16 weights

    wq_kernel<<<1, 256, 0, stream>>>(w, wsf, wbuf);
    conv_kernel<<<XN * 256, 256, 0, stream>>>(x, wbuf, wsf, bias, out);
}

// Round 3
// 313.778 us; speedup vs baseline: 1.0812x; 1.0812x over previous
//
#include <hip/hip_runtime.h>
#include <hip/hip_bf16.h>

typedef __attribute__((ext_vector_type(8))) short short8;
typedef __attribute__((ext_vector_type(4))) float f32x4;
typedef unsigned short u16;
typedef __attribute__((ext_vector_type(8))) unsigned short u16x8;

#define XN 16
#define XC 64
#define XH 256
#define XW 256
#define XO 64
#define CH_STRIDE (XH * XW)   // 65536

#define TILE_H 8
#define TILE_W 32
#define HALO_H 10
#define HALO_W 34
#define NPIX (HALO_H * HALO_W)   // 340
#define NPIX_PAD 344

// ws layout (bytes)
#define QX_OFF    0                          // u16[1048576*64] = 134,217,728 B (bf16, NHWC, xor-swizzled)
#define INVS_OFF  134217728                  // f32[1048576]    =   4,194,304 B
#define WBUF_OFF  138412032                  // u16[36864]      =      73,728 B
#define PART_OFF  138485760                  // f32[64]
#define WM_OFF    138486016                  // f32[1]
#define WS_NEED   138486272

// ---------------------------------------------------------------------------
// Weight quant, stage 1: deterministic partial |w| sums (64 blocks).
// w has XO*XC*9 = 36,864 ELEMENTS -> 576 per block (round-2 bug: used 2304,
// the byte-count/64, reading 4x OOB -> garbage mean).
// ---------------------------------------------------------------------------
__global__ __launch_bounds__(256) void wq_reduce(const float* __restrict__ w,
                                                 float* __restrict__ partials) {
    __shared__ float red[4];
    const int tid = threadIdx.x;
    const int base = blockIdx.x * 576;       // 36864 / 64
    float s = 0.f;
    for (int i = tid; i < 576; i += 256) s += fabsf(w[base + i]);
    #pragma unroll
    for (int off = 32; off > 0; off >>= 1) s += __shfl_down(s, off, 64);
    if ((tid & 63) == 0) red[tid >> 6] = s;
    __syncthreads();
    if (tid == 0) partials[blockIdx.x] = red[0] + red[1] + red[2] + red[3];
}

// ---------------------------------------------------------------------------
// Weight quant, stage 2: ternarize into MFMA A-fragment layout (144 blocks).
//   idx = (((t*4 + m)*2 + c)*64 + lane)*8 + j
//   holds tern[o = m*16 + (lane&15)][i = c*32 + (lane>>4)*8 + j][tap t]
// ---------------------------------------------------------------------------
__global__ __launch_bounds__(256) void wq_tern(const float* __restrict__ w,
                                               const float* __restrict__ partials,
                                               float* __restrict__ wm_out,
                                               u16* __restrict__ wbuf) {
    __shared__ float wm_sh;
    const int tid = threadIdx.x;
    if (tid == 0) {
        float tot = 0.f;
        #pragma unroll
        for (int i = 0; i < 64; ++i) tot += partials[i];   // fixed order: deterministic
        float wm = fmaxf(tot / (float)(XO * XC * 9), 1e-5f);
        wm_sh = wm;
        if (blockIdx.x == 0) wm_out[0] = wm;
    }
    __syncthreads();
    const float wscale = 1.0f / wm_sh;

    const int idx = blockIdx.x * 256 + tid;  // < 36864
    const int j = idx & 7;
    const int l = (idx >> 3) & 63;
    const int c = (idx >> 9) & 1;
    const int m = (idx >> 10) & 3;
    const int t = idx >> 12;
    const int o = m * 16 + (l & 15);
    const int i = c * 32 + (l >> 4) * 8 + j;
    const int kh = t / 3, kw = t % 3;
    const float wv = w[((o * XC + i) * 3 + kh) * 3 + kw];
    const float tern = fminf(fmaxf(rintf(wv * wscale), -1.f), 1.f);
    wbuf[idx] = (u16)(__float_as_uint(tern) >> 16);   // exact in bf16
}

// ---------------------------------------------------------------------------
// Activation quant: one block per (n,h) image row of 256 pixels.
// Writes qx pixel-major (128 B/pixel, channels contiguous), chunk cb stored at
// slot cb ^ (gw&7)  (xor-swizzle baked into global layout), plus invscale f32.
// ---------------------------------------------------------------------------
__global__ __launch_bounds__(256) void aq_kernel(const float* __restrict__ x,
                                                 u16* __restrict__ qx,
                                                 float* __restrict__ invs) {
    __shared__ __align__(16) u16 lds[256 * 64];   // 32 KiB
    const int tid = threadIdx.x;
    const int b = blockIdx.x;        // 4096 = 16*256
    const int n = b >> 8;
    const int hr = b & 255;

    const float* px = x + (size_t)n * (XC * CH_STRIDE) + (size_t)hr * XW + tid;
    float vals[64];
    float amax = 0.f;
    #pragma unroll
    for (int c = 0; c < 64; ++c) {
        const float v = px[(size_t)c * CH_STRIDE];
        vals[c] = v;
        amax = fmaxf(amax, fabsf(v));
    }
    const float am = fmaxf(amax, 1e-5f);
    const float scale = 127.0f / am;
    invs[(size_t)b * 256 + tid] = am * (1.0f / 127.0f);

    const int sw = (tid & 7) << 3;   // gw&7 == tid&7 here
    #pragma unroll
    for (int cb = 0; cb < 8; ++cb) {
        u16x8 pk;
        #pragma unroll
        for (int j = 0; j < 8; ++j) {
            const float q = fminf(fmaxf(rintf(vals[cb * 8 + j] * scale), -128.f), 127.f);
            pk[j] = (u16)(__float_as_uint(q) >> 16);   // exact int in bf16
        }
        *reinterpret_cast<u16x8*>(&lds[tid * 64 + ((cb * 8) ^ sw)]) = pk;
    }
    __syncthreads();

    // coalesced 32 KiB LDS -> global copy (verbatim, swizzle preserved)
    u16* dst = qx + (size_t)b * 16384;
    #pragma unroll
    for (int i = 0; i < 8; ++i) {
        *reinterpret_cast<u16x8*>(dst + i * 2048 + tid * 8) =
            *reinterpret_cast<const u16x8*>(lds + i * 2048 + tid * 8);
    }
}

// ---------------------------------------------------------------------------
// Conv: stage pre-quantized bf16 halo tile (verbatim 16 B copies) + MFMA.
// Read-side swizzle key = gw&7 = (l15 + dw - 1) & 7  (w0 % 8 == 0, 16 % 8 == 0).
// Out-of-image halo pixels stage clamped data but get invscale 0.
// ---------------------------------------------------------------------------
__global__ __launch_bounds__(256) void conv_q_kernel(const u16* __restrict__ qx,
                                                     const float* __restrict__ invs,
                                                     const u16* __restrict__ wbuf,
                                                     const float* __restrict__ wm_ptr,
                                                     const float* __restrict__ bias,
                                                     float* __restrict__ out) {
    __shared__ __align__(16) u16 q_lds[NPIX_PAD * 64];   // 44,032 B
    __shared__ float invs_lds[NPIX];
    __shared__ float bias_lds[XO];

    const int tid = threadIdx.x;
    const int bid = blockIdx.x;
    const int n   = bid >> 8;
    const int rem = bid & 255;
    const int h0  = (rem >> 3) << 3;
    const int w0  = (rem & 7) << 5;

    if (tid < XO) bias_lds[tid] = bias[tid];

    // ---- stage qx halo: 344 px * 8 chunks of 16 B, verbatim ----
    for (int idx = tid; idx < NPIX_PAD * 8; idx += 256) {
        const int p  = idx >> 3;
        const int ck = idx & 7;
        const int hrow = p / HALO_W;
        const int cl   = p - hrow * HALO_W;
        const int gh = h0 + hrow - 1;
        const int gw = w0 + cl - 1;
        const int ghc = min(max(gh, 0), XH - 1);
        const int gwc = min(max(gw, 0), XW - 1);
        const size_t P = ((size_t)n << 16) + ((size_t)ghc << 8) + (size_t)gwc;
        *reinterpret_cast<u16x8*>(&q_lds[(size_t)idx * 8]) =
            *reinterpret_cast<const u16x8*>(qx + P * 64 + ck * 8);
    }
    // ---- stage invscale (0 for out-of-image -> kills garbage contributions) ----
    for (int p = tid; p < NPIX; p += 256) {
        const int hrow = p / HALO_W;
        const int cl   = p - hrow * HALO_W;
        const int gh = h0 + hrow - 1;
        const int gw = w0 + cl - 1;
        const bool ok = (gh >= 0) & (gh < XH) & (gw >= 0) & (gw < XW);
        const int ghc = min(max(gh, 0), XH - 1);
        const int gwc = min(max(gw, 0), XW - 1);
        invs_lds[p] = ok ? invs[((size_t)n << 16) + ((size_t)ghc << 8) + (size_t)gwc] : 0.f;
    }
    __syncthreads();

    const int lane = tid & 63;
    const int wv   = tid >> 6;
    const int l15  = lane & 15;
    const int lg   = lane >> 4;

    f32x4 acc[4][4];
    #pragma unroll
    for (int m = 0; m < 4; ++m)
        #pragma unroll
        for (int nt = 0; nt < 4; ++nt) acc[m][nt] = (f32x4){0.f, 0.f, 0.f, 0.f};

    const float wm = wm_ptr[0];

    #pragma unroll
    for (int t = 0; t < 9; ++t) {
        const int dh = t / 3, dw = t % 3;

        short8 afr[4][2];
        #pragma unroll
        for (int m = 0; m < 4; ++m)
            #pragma unroll
            for (int c = 0; c < 2; ++c)
                afr[m][c] = *reinterpret_cast<const short8*>(
                    wbuf + ((((t * 4 + m) * 2 + c) * 64 + lane) * 8));

        const int sw = ((l15 + dw + 7) & 7) << 3;   // storage key = gw&7

        #pragma unroll
        for (int nt = 0; nt < 4; ++nt) {
            const int rl  = 2 * wv + (nt >> 1);
            const int pix = (rl + dh) * HALO_W + (nt & 1) * 16 + l15 + dw;
            const u16* qp = &q_lds[pix * 64];
            const short8 b0 = *reinterpret_cast<const short8*>(qp + ((lg * 8) ^ sw));
            const short8 b1 = *reinterpret_cast<const short8*>(qp + ((32 + lg * 8) ^ sw));
            const float  iv = invs_lds[pix];
            #pragma unroll
            for (int m = 0; m < 4; ++m) {
                f32x4 tap = (f32x4){0.f, 0.f, 0.f, 0.f};
                tap = __builtin_amdgcn_mfma_f32_16x16x32_bf16(afr[m][0], b0, tap, 0, 0, 0);
                tap = __builtin_amdgcn_mfma_f32_16x16x32_bf16(afr[m][1], b1, tap, 0, 0, 0);
                acc[m][nt] += tap * iv;
            }
        }
    }

    #pragma unroll
    for (int m = 0; m < 4; ++m) {
        #pragma unroll
        for (int nt = 0; nt < 4; ++nt) {
            const int rl = 2 * wv + (nt >> 1);
            const int gh = h0 + rl;
            const int gw = w0 + (nt & 1) * 16 + l15;
            #pragma unroll
            for (int r = 0; r < 4; ++r) {
                const int o = m * 16 + lg * 4 + r;
                const float v = wm * acc[m][nt][r] + bias_lds[o];
                out[(((size_t)n * XO + o) * XH + gh) * XW + gw] = v;
            }
        }
    }
}

// ===========================================================================
// Fallback (round-1, verified): fused kernel pair, needs only ~74 KB of ws.
// ===========================================================================
__global__ __launch_bounds__(256) void wq_kernel(const float* __restrict__ w,
                                                 float* __restrict__ wm_out,
                                                 u16* __restrict__ wbuf) {
    __shared__ float red[4];
    __shared__ float wm_sh;
    const int tid = threadIdx.x;

    float s = 0.f;
    for (int i = tid; i < XO * XC * 9; i += 256) s += fabsf(w[i]);
    #pragma unroll
    for (int off = 32; off > 0; off >>= 1) s += __shfl_down(s, off, 64);
    if ((tid & 63) == 0) red[tid >> 6] = s;
    __syncthreads();
    if (tid == 0) {
        float tot = red[0] + red[1] + red[2] + red[3];
        float wm = fmaxf(tot / (float)(XO * XC * 9), 1e-5f);
        wm_out[0] = wm;
        wm_sh = wm;
    }
    __syncthreads();
    const float wscale = 1.0f / wm_sh;

    for (int idx = tid; idx < XO * XC * 9; idx += 256) {
        const int j = idx & 7;
        const int l = (idx >> 3) & 63;
        const int c = (idx >> 9) & 1;
        const int m = (idx >> 10) & 3;
        const int t = idx >> 12;
        const int o = m * 16 + (l & 15);
        const int i = c * 32 + (l >> 4) * 8 + j;
        const int kh = t / 3, kw = t % 3;
        const float wv = w[((o * XC + i) * 3 + kh) * 3 + kw];
        const float tern = fminf(fmaxf(rintf(wv * wscale), -1.f), 1.f);
        wbuf[idx] = (u16)(__float_as_uint(tern) >> 16);
    }
}

__global__ __launch_bounds__(256) void conv_kernel(const float* __restrict__ x,
                                                   const u16* __restrict__ wbuf,
                                                   const float* __restrict__ wm_ptr,
                                                   const float* __restrict__ bias,
                                                   float* __restrict__ out) {
    __shared__ __align__(16) u16 q_lds[NPIX * 64];
    __shared__ float invs_lds[NPIX];
    __shared__ float bias_lds[XO];

    const int tid = threadIdx.x;
    const int bid = blockIdx.x;
    const int n   = bid >> 8;
    const int rem = bid & 255;
    const int h0  = (rem >> 3) << 3;
    const int w0  = (rem & 7) << 5;

    if (tid < XO) bias_lds[tid] = bias[tid];

    #pragma unroll 1
    for (int p = tid; p < NPIX; p += 256) {
        const int hr = p / HALO_W;
        const int cl = p - hr * HALO_W;
        const int gh = h0 + hr - 1;
        const int gw = w0 + cl - 1;
        const bool ok = (gh >= 0) & (gh < XH) & (gw >= 0) & (gw < XW);

        float vals[64];
        float amax = 0.f;
        if (ok) {
            const float* px = x + (size_t)n * (XC * CH_STRIDE) + (size_t)gh * XW + gw;
            #pragma unroll
            for (int c = 0; c < 64; ++c) {
                const float v = px[(size_t)c * CH_STRIDE];
                vals[c] = v;
                amax = fmaxf(amax, fabsf(v));
            }
        } else {
            #pragma unroll
            for (int c = 0; c < 64; ++c) vals[c] = 0.f;
        }
        const float am    = fmaxf(amax, 1e-5f);
        const float scale = 127.0f / am;
        invs_lds[p] = ok ? (1.0f / scale) : 0.0f;

        const int sw = (p & 7) << 3;
        #pragma unroll
        for (int cb = 0; cb < 8; ++cb) {
            u16x8 pk;
            #pragma unroll
            for (int j = 0; j < 8; ++j) {
                const float q = fminf(fmaxf(rintf(vals[cb * 8 + j] * scale), -128.f), 127.f);
                pk[j] = (u16)(__float_as_uint(q) >> 16);
            }
            *reinterpret_cast<u16x8*>(&q_lds[p * 64 + ((cb * 8) ^ sw)]) = pk;
        }
    }
    __syncthreads();

    const int lane = tid & 63;
    const int wv   = tid >> 6;
    const int l15  = lane & 15;
    const int lg   = lane >> 4;

    f32x4 acc[4][4];
    #pragma unroll
    for (int m = 0; m < 4; ++m)
        #pragma unroll
        for (int nt = 0; nt < 4; ++nt) acc[m][nt] = (f32x4){0.f, 0.f, 0.f, 0.f};

    const float wm = wm_ptr[0];

    #pragma unroll
    for (int t = 0; t < 9; ++t) {
        const int dh = t / 3, dw = t % 3;

        short8 afr[4][2];
        #pragma unroll
        for (int m = 0; m < 4; ++m)
            #pragma unroll
            for (int c = 0; c < 2; ++c)
                afr[m][c] = *reinterpret_cast<const short8*>(
                    wbuf + ((((t * 4 + m) * 2 + c) * 64 + lane) * 8));

        #pragma unroll
        for (int nt = 0; nt < 4; ++nt) {
            const int rl  = 2 * wv + (nt >> 1);
            const int pix = (rl + dh) * HALO_W + (nt & 1) * 16 + l15 + dw;
            const int sw  = (pix & 7) << 3;
            const u16* qp = &q_lds[pix * 64];
            const short8 b0 = *reinterpret_cast<const short8*>(qp + ((lg * 8) ^ sw));
            const short8 b1 = *reinterpret_cast<const short8*>(qp + ((32 + lg * 8) ^ sw));
            const float  iv = invs_lds[pix];
            #pragma unroll
            for (int m = 0; m < 4; ++m) {
                f32x4 tap = (f32x4){0.f, 0.f, 0.f, 0.f};
                tap = __builtin_amdgcn_mfma_f32_16x16x32_bf16(afr[m][0], b0, tap, 0, 0, 0);
                tap = __builtin_amdgcn_mfma_f32_16x16x32_bf16(afr[m][1], b1, tap, 0, 0, 0);
                acc[m][nt] += tap * iv;
            }
        }
    }

    #pragma unroll
    for (int m = 0; m < 4; ++m) {
        #pragma unroll
        for (int nt = 0; nt < 4; ++nt) {
            const int rl = 2 * wv + (nt >> 1);
            const int gh = h0 + rl;
            const int gw = w0 + (nt & 1) * 16 + l15;
            #pragma unroll
            for (int r = 0; r < 4; ++r) {
                const int o = m * 16 + lg * 4 + r;
                const float v = wm * acc[m][nt][r] + bias_lds[o];
                out[(((size_t)n * XO + o) * XH + gh) * XW + gw] = v;
            }
        }
    }
}

extern "C" void kernel_launch(void* const* d_in, const int* in_sizes, int n_in,
                              void* d_out, int out_size, void* d_ws, size_t ws_size,
                              hipStream_t stream) {
    const float* x    = (const float*)d_in[0];
    const float* w    = (const float*)d_in[1];
    const float* bias = (const float*)d_in[2];
    float* out = (float*)d_out;

    if (ws_size >= (size_t)WS_NEED) {
        u16*   qx       = (u16*)d_ws;
        float* invsb    = (float*)((char*)d_ws + INVS_OFF);
        u16*   wbuf     = (u16*)((char*)d_ws + WBUF_OFF);
        float* partials = (float*)((char*)d_ws + PART_OFF);
        float* wm       = (float*)((char*)d_ws + WM_OFF);

        wq_reduce<<<64, 256, 0, stream>>>(w, partials);
        wq_tern<<<144, 256, 0, stream>>>(w, partials, wm, wbuf);
        aq_kernel<<<XN * 256, 256, 0, stream>>>(x, qx, invsb);
        conv_q_kernel<<<XN * 256, 256, 0, stream>>>(qx, invsb, wbuf, wm, bias, out);
    } else {
        float* wsf  = (float*)d_ws;
        u16*   wbuf = (u16*)((char*)d_ws + 64);
        wq_kernel<<<1, 256, 0, stream>>>(w, wsf, wbuf);
        conv_kernel<<<XN * 256, 256, 0, stream>>>(x, wbuf, wsf, bias, out);
    }
}

// Round 4
// 277.706 us; speedup vs baseline: 1.2217x; 1.1299x over previous
//
#include <hip/hip_runtime.h>
#include <hip/hip_bf16.h>

typedef __attribute__((ext_vector_type(8))) short short8;
typedef __attribute__((ext_vector_type(4))) float f32x4;
typedef __attribute__((ext_vector_type(4))) int i32x4;
typedef unsigned short u16;
typedef unsigned int u32;
typedef __attribute__((ext_vector_type(8))) unsigned short u16x8;
typedef __attribute__((ext_vector_type(4))) u32 u32x4;

#define XN 16
#define XC 64
#define XH 256
#define XW 256
#define XO 64
#define CH_STRIDE (XH * XW)   // 65536

// ---- i8 path ws layout (bytes) ----
#define QX_OFF    0                         // i8[16*256*256*64] = 67,108,864 (pixel-major NHWC)
#define INVS_OFF  67108864                  // f32[1048576] = 4,194,304
#define WBUF_OFF  71303168                  // i8[36864]
#define PART_OFF  71340032                  // f32[64]
#define WM_OFF    71340288                  // f32[1]
#define WS_NEED   71340544

// ---------------------------------------------------------------------------
// Weight quant stage 1: deterministic partial |w| sums (64 blocks x 576 elems).
// ---------------------------------------------------------------------------
__global__ __launch_bounds__(256) void wq_reduce(const float* __restrict__ w,
                                                 float* __restrict__ partials) {
    __shared__ float red[4];
    const int tid = threadIdx.x;
    const int base = blockIdx.x * 576;       // 36864 / 64
    float s = 0.f;
    for (int i = tid; i < 576; i += 256) s += fabsf(w[base + i]);
    #pragma unroll
    for (int off = 32; off > 0; off >>= 1) s += __shfl_down(s, off, 64);
    if ((tid & 63) == 0) red[tid >> 6] = s;
    __syncthreads();
    if (tid == 0) partials[blockIdx.x] = red[0] + red[1] + red[2] + red[3];
}

// ---------------------------------------------------------------------------
// Weight quant stage 2: ternarize to i8 in MFMA A-fragment layout (144 blocks).
//   idx = ((t*4 + m)*64 + l)*16 + j
//   holds tern[o = m*16 + (l&15)][i = (l>>4)*16 + j]  for tap t
// ---------------------------------------------------------------------------
__global__ __launch_bounds__(256) void wq_tern_i8(const float* __restrict__ w,
                                                  const float* __restrict__ partials,
                                                  float* __restrict__ wm_out,
                                                  signed char* __restrict__ wbuf) {
    __shared__ float wm_sh;
    const int tid = threadIdx.x;
    if (tid == 0) {
        float tot = 0.f;
        #pragma unroll
        for (int i = 0; i < 64; ++i) tot += partials[i];   // fixed order: deterministic
        float wm = fmaxf(tot / (float)(XO * XC * 9), 1e-5f);
        wm_sh = wm;
        if (blockIdx.x == 0) wm_out[0] = wm;
    }
    __syncthreads();
    const float wscale = 1.0f / wm_sh;

    const int idx = blockIdx.x * 256 + tid;  // < 36864
    const int j = idx & 15;
    const int l = (idx >> 4) & 63;
    const int m = (idx >> 10) & 3;
    const int t = idx >> 12;                 // 0..8
    const int o = m * 16 + (l & 15);
    const int i = (l >> 4) * 16 + j;
    const int kh = t / 3, kw = t % 3;
    const float wv = w[((o * XC + i) * 3 + kh) * 3 + kw];
    const float tern = fminf(fmaxf(rintf(wv * wscale), -1.f), 1.f);
    wbuf[idx] = (signed char)(int)tern;
}

// ---------------------------------------------------------------------------
// Activation quant: one block per (n,h) row. qx = i8, pixel-major (64 B/px,
// channels contiguous, NO swizzle). invs = amax/127 per pixel.
// ---------------------------------------------------------------------------
__global__ __launch_bounds__(256) void aq_i8(const float* __restrict__ x,
                                             signed char* __restrict__ qx,
                                             float* __restrict__ invs) {
    const int tid = threadIdx.x;
    const int b = blockIdx.x;            // 4096 = 16*256
    const int n = b >> 8;

    const float* px = x + ((size_t)n << 22) + ((size_t)(b & 255) << 8) + tid;
    float vals[64];
    float amax = 0.f;
    #pragma unroll
    for (int c = 0; c < 64; ++c) {
        const float v = px[(size_t)c << 16];
        vals[c] = v;
        amax = fmaxf(amax, fabsf(v));
    }
    const float am = fmaxf(amax, 1e-5f);
    const float scale = 127.0f / am;
    invs[((size_t)b << 8) + tid] = am * (1.0f / 127.0f);

    // pack 64 quantized ints into 16 words, write as 4x16B (contiguous per thread)
    u32 words[16];
    #pragma unroll
    for (int wk = 0; wk < 16; ++wk) {
        u32 acc = 0;
        #pragma unroll
        for (int bb = 0; bb < 4; ++bb) {
            const float q = fminf(fmaxf(rintf(vals[wk * 4 + bb] * scale), -128.f), 127.f);
            acc |= ((u32)((int)q) & 255u) << (bb * 8);
        }
        words[wk] = acc;
    }
    u32* dst = (u32*)(qx + ((((size_t)b << 8) + tid) << 6));
    #pragma unroll
    for (int i = 0; i < 4; ++i) {
        *reinterpret_cast<u32x4*>(dst + i * 4) =
            (u32x4){words[i * 4], words[i * 4 + 1], words[i * 4 + 2], words[i * 4 + 3]};
    }
}

// ---------------------------------------------------------------------------
// Conv: no LDS, no barriers. Wave = 1 output row x 32 px x 64 out-ch.
// Block = 4 waves = 4 consecutive rows (L1 halo sharing). 8192 blocks, XCD-swizzled.
// Per tap: B = one 16B global load (full K=64 pixel channel vector),
// one mfma_i32_16x16x64_i8 per (m,nt); acc_f32 += cvt(tap)*iv (iv has wm folded).
// ---------------------------------------------------------------------------
__global__ __launch_bounds__(256, 4) void conv_i8(const signed char* __restrict__ qx,
                                                  const float* __restrict__ invs,
                                                  const signed char* __restrict__ wbuf,
                                                  const float* __restrict__ wm_ptr,
                                                  const float* __restrict__ bias,
                                                  float* __restrict__ out) {
    const int tid = threadIdx.x;
    // bijective XCD swizzle: 8192 blocks % 8 == 0
    const int bid = (blockIdx.x & 7) * 1024 + (blockIdx.x >> 3);
    const int n      = bid >> 9;           // 512 blocks/image
    const int rem    = bid & 511;
    const int rowgrp = rem >> 3;           // 0..63
    const int w0     = (rem & 7) << 5;     // 0..224
    const int wv     = tid >> 6;
    const int gh_out = (rowgrp << 2) + wv; // this wave's output row
    const int lane = tid & 63;
    const int l15 = lane & 15;
    const int lg  = lane >> 4;

    const float wm = wm_ptr[0];

    const signed char* qn = qx + ((size_t)n << 22);          // n * 256*256*64
    const float*       in = invs + ((size_t)n << 16);

    f32x4 acc[4][2];
    #pragma unroll
    for (int m = 0; m < 4; ++m) {
        acc[m][0] = (f32x4){0.f, 0.f, 0.f, 0.f};
        acc[m][1] = (f32x4){0.f, 0.f, 0.f, 0.f};
    }

    // per-lane clamped cols for nt in {0,1}, dw in {0,1,2}
    int gwc[2][3]; bool cok[2][3];
    #pragma unroll
    for (int nt = 0; nt < 2; ++nt)
        #pragma unroll
        for (int dw = 0; dw < 3; ++dw) {
            const int gw = w0 + nt * 16 + l15 + dw - 1;
            cok[nt][dw] = (gw >= 0) & (gw < XW);
            gwc[nt][dw] = min(max(gw, 0), XW - 1);
        }

    #pragma unroll
    for (int dh = 0; dh < 3; ++dh) {
        const int gh = gh_out + dh - 1;
        const bool rok = (gh >= 0) & (gh < XH);
        const int ghc = min(max(gh, 0), XH - 1);
        const signed char* qrow = qn + ((size_t)ghc << 14);   // 256 px * 64 B
        const float*       irow = in + (ghc << 8);

        #pragma unroll
        for (int dw = 0; dw < 3; ++dw) {
            const int t = dh * 3 + dw;

            i32x4 b[2]; float iv[2];
            #pragma unroll
            for (int nt = 0; nt < 2; ++nt) {
                const int c = gwc[nt][dw];
                b[nt] = *reinterpret_cast<const i32x4*>(qrow + (c << 6) + (lg << 4));
                const float ivv = irow[c];
                iv[nt] = (rok & cok[nt][dw]) ? ivv * wm : 0.f;
            }

            #pragma unroll
            for (int m = 0; m < 4; ++m) {
                const i32x4 af = *reinterpret_cast<const i32x4*>(
                    wbuf + (((t << 2) + m) << 10) + (lane << 4));
                #pragma unroll
                for (int nt = 0; nt < 2; ++nt) {
                    i32x4 tap = __builtin_amdgcn_mfma_i32_16x16x64_i8(
                        af, b[nt], (i32x4){0, 0, 0, 0}, 0, 0, 0);
                    f32x4 tf;
                    tf[0] = (float)tap[0]; tf[1] = (float)tap[1];
                    tf[2] = (float)tap[2]; tf[3] = (float)tap[3];
                    acc[m][nt] += tf * iv[nt];
                }
            }
        }
    }

    // epilogue: D col = l15 (pixel), row = lg*4 + r (out-ch within m-tile)
    #pragma unroll
    for (int m = 0; m < 4; ++m) {
        #pragma unroll
        for (int r = 0; r < 4; ++r) {
            const int o = (m << 4) + (lg << 2) + r;
            const float bz = bias[o];
            float* orow = out + ((((size_t)n << 6) + o) << 16) + (gh_out << 8) + w0;
            orow[l15]      = acc[m][0][r] + bz;
            orow[16 + l15] = acc[m][1][r] + bz;
        }
    }
}

// ===========================================================================
// Fallback (round-1, verified): fused bf16 kernel pair, needs ~74 KB of ws.
// ===========================================================================
#define HALO_W 34
#define NPIX 340

__global__ __launch_bounds__(256) void wq_kernel(const float* __restrict__ w,
                                                 float* __restrict__ wm_out,
                                                 u16* __restrict__ wbuf) {
    __shared__ float red[4];
    __shared__ float wm_sh;
    const int tid = threadIdx.x;

    float s = 0.f;
    for (int i = tid; i < XO * XC * 9; i += 256) s += fabsf(w[i]);
    #pragma unroll
    for (int off = 32; off > 0; off >>= 1) s += __shfl_down(s, off, 64);
    if ((tid & 63) == 0) red[tid >> 6] = s;
    __syncthreads();
    if (tid == 0) {
        float tot = red[0] + red[1] + red[2] + red[3];
        float wm = fmaxf(tot / (float)(XO * XC * 9), 1e-5f);
        wm_out[0] = wm;
        wm_sh = wm;
    }
    __syncthreads();
    const float wscale = 1.0f / wm_sh;

    for (int idx = tid; idx < XO * XC * 9; idx += 256) {
        const int j = idx & 7;
        const int l = (idx >> 3) & 63;
        const int c = (idx >> 9) & 1;
        const int m = (idx >> 10) & 3;
        const int t = idx >> 12;
        const int o = m * 16 + (l & 15);
        const int i = c * 32 + (l >> 4) * 8 + j;
        const int kh = t / 3, kw = t % 3;
        const float wv = w[((o * XC + i) * 3 + kh) * 3 + kw];
        const float tern = fminf(fmaxf(rintf(wv * wscale), -1.f), 1.f);
        wbuf[idx] = (u16)(__float_as_uint(tern) >> 16);
    }
}

__global__ __launch_bounds__(256) void conv_kernel(const float* __restrict__ x,
                                                   const u16* __restrict__ wbuf,
                                                   const float* __restrict__ wm_ptr,
                                                   const float* __restrict__ bias,
                                                   float* __restrict__ out) {
    __shared__ __align__(16) u16 q_lds[NPIX * 64];
    __shared__ float invs_lds[NPIX];
    __shared__ float bias_lds[XO];

    const int tid = threadIdx.x;
    const int bid = blockIdx.x;
    const int n   = bid >> 8;
    const int rem = bid & 255;
    const int h0  = (rem >> 3) << 3;
    const int w0  = (rem & 7) << 5;

    if (tid < XO) bias_lds[tid] = bias[tid];

    #pragma unroll 1
    for (int p = tid; p < NPIX; p += 256) {
        const int hr = p / HALO_W;
        const int cl = p - hr * HALO_W;
        const int gh = h0 + hr - 1;
        const int gw = w0 + cl - 1;
        const bool ok = (gh >= 0) & (gh < XH) & (gw >= 0) & (gw < XW);

        float vals[64];
        float amax = 0.f;
        if (ok) {
            const float* px = x + (size_t)n * (XC * CH_STRIDE) + (size_t)gh * XW + gw;
            #pragma unroll
            for (int c = 0; c < 64; ++c) {
                const float v = px[(size_t)c * CH_STRIDE];
                vals[c] = v;
                amax = fmaxf(amax, fabsf(v));
            }
        } else {
            #pragma unroll
            for (int c = 0; c < 64; ++c) vals[c] = 0.f;
        }
        const float am    = fmaxf(amax, 1e-5f);
        const float scale = 127.0f / am;
        invs_lds[p] = ok ? (1.0f / scale) : 0.0f;

        const int sw = (p & 7) << 3;
        #pragma unroll
        for (int cb = 0; cb < 8; ++cb) {
            u16x8 pk;
            #pragma unroll
            for (int j = 0; j < 8; ++j) {
                const float q = fminf(fmaxf(rintf(vals[cb * 8 + j] * scale), -128.f), 127.f);
                pk[j] = (u16)(__float_as_uint(q) >> 16);
            }
            *reinterpret_cast<u16x8*>(&q_lds[p * 64 + ((cb * 8) ^ sw)]) = pk;
        }
    }
    __syncthreads();

    const int lane = tid & 63;
    const int wv   = tid >> 6;
    const int l15  = lane & 15;
    const int lg   = lane >> 4;

    f32x4 acc[4][4];
    #pragma unroll
    for (int m = 0; m < 4; ++m)
        #pragma unroll
        for (int nt = 0; nt < 4; ++nt) acc[m][nt] = (f32x4){0.f, 0.f, 0.f, 0.f};

    const float wm = wm_ptr[0];

    #pragma unroll
    for (int t = 0; t < 9; ++t) {
        const int dh = t / 3, dw = t % 3;

        short8 afr[4][2];
        #pragma unroll
        for (int m = 0; m < 4; ++m)
            #pragma unroll
            for (int c = 0; c < 2; ++c)
                afr[m][c] = *reinterpret_cast<const short8*>(
                    wbuf + ((((t * 4 + m) * 2 + c) * 64 + lane) * 8));

        #pragma unroll
        for (int nt = 0; nt < 4; ++nt) {
            const int rl  = 2 * wv + (nt >> 1);
            const int pix = (rl + dh) * HALO_W + (nt & 1) * 16 + l15 + dw;
            const int sw  = (pix & 7) << 3;
            const u16* qp = &q_lds[pix * 64];
            const short8 b0 = *reinterpret_cast<const short8*>(qp + ((lg * 8) ^ sw));
            const short8 b1 = *reinterpret_cast<const short8*>(qp + ((32 + lg * 8) ^ sw));
            const float  iv = invs_lds[pix];
            #pragma unroll
            for (int m = 0; m < 4; ++m) {
                f32x4 tap = (f32x4){0.f, 0.f, 0.f, 0.f};
                tap = __builtin_amdgcn_mfma_f32_16x16x32_bf16(afr[m][0], b0, tap, 0, 0, 0);
                tap = __builtin_amdgcn_mfma_f32_16x16x32_bf16(afr[m][1], b1, tap, 0, 0, 0);
                acc[m][nt] += tap * iv;
            }
        }
    }

    #pragma unroll
    for (int m = 0; m < 4; ++m) {
        #pragma unroll
        for (int nt = 0; nt < 4; ++nt) {
            const int rl = 2 * wv + (nt >> 1);
            const int gh = h0 + rl;
            const int gw = w0 + (nt & 1) * 16 + l15;
            #pragma unroll
            for (int r = 0; r < 4; ++r) {
                const int o = m * 16 + lg * 4 + r;
                const float v = wm * acc[m][nt][r] + bias_lds[o];
                out[(((size_t)n * XO + o) * XH + gh) * XW + gw] = v;
            }
        }
    }
}

extern "C" void kernel_launch(void* const* d_in, const int* in_sizes, int n_in,
                              void* d_out, int out_size, void* d_ws, size_t ws_size,
                              hipStream_t stream) {
    const float* x    = (const float*)d_in[0];
    const float* w    = (const float*)d_in[1];
    const float* bias = (const float*)d_in[2];
    float* out = (float*)d_out;

    if (ws_size >= (size_t)WS_NEED) {
        signed char* qx       = (signed char*)d_ws;
        float*       invsb    = (float*)((char*)d_ws + INVS_OFF);
        signed char* wbuf     = (signed char*)((char*)d_ws + WBUF_OFF);
        float*       partials = (float*)((char*)d_ws + PART_OFF);
        float*       wm       = (float*)((char*)d_ws + WM_OFF);

        wq_reduce<<<64, 256, 0, stream>>>(w, partials);
        wq_tern_i8<<<144, 256, 0, stream>>>(w, partials, wm, wbuf);
        aq_i8<<<XN * 256, 256, 0, stream>>>(x, qx, invsb);
        conv_i8<<<XN * 512, 256, 0, stream>>>(qx, invsb, wbuf, wm, bias, out);
    } else {
        float* wsf  = (float*)d_ws;
        u16*   wbuf = (u16*)((char*)d_ws + 64);
        wq_kernel<<<1, 256, 0, stream>>>(w, wsf, wbuf);
        conv_kernel<<<XN * 256, 256, 0, stream>>>(x, wbuf, wsf, bias, out);
    }
}

// Round 5
// 268.370 us; speedup vs baseline: 1.2642x; 1.0348x over previous
//
#include <hip/hip_runtime.h>
#include <hip/hip_bf16.h>

typedef __attribute__((ext_vector_type(8))) short short8;
typedef __attribute__((ext_vector_type(4))) float f32x4;
typedef __attribute__((ext_vector_type(4))) int i32x4;
typedef unsigned short u16;
typedef unsigned int u32;
typedef __attribute__((ext_vector_type(8))) unsigned short u16x8;
typedef __attribute__((ext_vector_type(4))) u32 u32x4;

#define XN 16
#define XC 64
#define XH 256
#define XW 256
#define XO 64
#define CH_STRIDE (XH * XW)   // 65536

// ---- i8 path ws layout (bytes) ----
#define QX_OFF    0                         // i8[16*256*256*64] = 67,108,864 (pixel-major NHWC)
#define INVS_OFF  67108864                  // f32[1048576] = 4,194,304
#define WBUF_OFF  71303168                  // i8[36864]
#define PART_OFF  71340032                  // f32[64]
#define WM_OFF    71340288                  // f32[1]
#define WS_NEED   71340544

// ---------------------------------------------------------------------------
// Weight quant stage 1: deterministic partial |w| sums (64 blocks x 576 elems).
// ---------------------------------------------------------------------------
__global__ __launch_bounds__(256) void wq_reduce(const float* __restrict__ w,
                                                 float* __restrict__ partials) {
    __shared__ float red[4];
    const int tid = threadIdx.x;
    const int base = blockIdx.x * 576;       // 36864 / 64
    float s = 0.f;
    for (int i = tid; i < 576; i += 256) s += fabsf(w[base + i]);
    #pragma unroll
    for (int off = 32; off > 0; off >>= 1) s += __shfl_down(s, off, 64);
    if ((tid & 63) == 0) red[tid >> 6] = s;
    __syncthreads();
    if (tid == 0) partials[blockIdx.x] = red[0] + red[1] + red[2] + red[3];
}

// ---------------------------------------------------------------------------
// Weight quant stage 2: ternarize to i8 in MFMA A-fragment layout (144 blocks).
//   idx = ((t*4 + m)*64 + l)*16 + j
//   holds tern[o = m*16 + (l&15)][i = (l>>4)*16 + j]  for tap t
// ---------------------------------------------------------------------------
__global__ __launch_bounds__(256) void wq_tern_i8(const float* __restrict__ w,
                                                  const float* __restrict__ partials,
                                                  float* __restrict__ wm_out,
                                                  signed char* __restrict__ wbuf) {
    __shared__ float wm_sh;
    const int tid = threadIdx.x;
    if (tid == 0) {
        float tot = 0.f;
        #pragma unroll
        for (int i = 0; i < 64; ++i) tot += partials[i];   // fixed order: deterministic
        float wm = fmaxf(tot / (float)(XO * XC * 9), 1e-5f);
        wm_sh = wm;
        if (blockIdx.x == 0) wm_out[0] = wm;
    }
    __syncthreads();
    const float wscale = 1.0f / wm_sh;

    const int idx = blockIdx.x * 256 + tid;  // < 36864
    const int j = idx & 15;
    const int l = (idx >> 4) & 63;
    const int m = (idx >> 10) & 3;
    const int t = idx >> 12;                 // 0..8
    const int o = m * 16 + (l & 15);
    const int i = (l >> 4) * 16 + j;
    const int kh = t / 3, kw = t % 3;
    const float wv = w[((o * XC + i) * 3 + kh) * 3 + kw];
    const float tern = fminf(fmaxf(rintf(wv * wscale), -1.f), 1.f);
    wbuf[idx] = (signed char)(int)tern;
}

// ---------------------------------------------------------------------------
// Activation quant: one block per (n,h) row. qx = i8, pixel-major (64 B/px,
// channels contiguous, NO swizzle). invs = amax/127 per pixel.
// ---------------------------------------------------------------------------
__global__ __launch_bounds__(256) void aq_i8(const float* __restrict__ x,
                                             signed char* __restrict__ qx,
                                             float* __restrict__ invs) {
    const int tid = threadIdx.x;
    const int b = blockIdx.x;            // 4096 = 16*256
    const int n = b >> 8;

    const float* px = x + ((size_t)n << 22) + ((size_t)(b & 255) << 8) + tid;
    float vals[64];
    float amax = 0.f;
    #pragma unroll
    for (int c = 0; c < 64; ++c) {
        const float v = px[(size_t)c << 16];
        vals[c] = v;
        amax = fmaxf(amax, fabsf(v));
    }
    const float am = fmaxf(amax, 1e-5f);
    const float scale = 127.0f / am;
    invs[((size_t)b << 8) + tid] = am * (1.0f / 127.0f);

    // pack 64 quantized ints into 16 words, write as 4x16B (contiguous per thread)
    u32 words[16];
    #pragma unroll
    for (int wk = 0; wk < 16; ++wk) {
        u32 acc = 0;
        #pragma unroll
        for (int bb = 0; bb < 4; ++bb) {
            const float q = fminf(fmaxf(rintf(vals[wk * 4 + bb] * scale), -128.f), 127.f);
            acc |= ((u32)((int)q) & 255u) << (bb * 8);
        }
        words[wk] = acc;
    }
    u32* dst = (u32*)(qx + ((((size_t)b << 8) + tid) << 6));
    #pragma unroll
    for (int i = 0; i < 4; ++i) {
        *reinterpret_cast<u32x4*>(dst + i * 4) =
            (u32x4){words[i * 4], words[i * 4 + 1], words[i * 4 + 2], words[i * 4 + 3]};
    }
}

// ---------------------------------------------------------------------------
// Conv v2: no LDS, no barriers. Wave = 1 output row x 32 px x 64 out-ch.
// ALL 18 B-fragments + 18 iv scalars hoisted into registers before the MFMA
// chain (single latency exposure instead of 18 serialized ones). A-fragments
// (36 KB L1/L2-resident table) load inside the unrolled tap loop, scheduled
// by the compiler against previous tap's MFMAs. wm folded into epilogue.
// __launch_bounds__(256,3): VGPR cap ~170 so the hoist stays in registers.
// ---------------------------------------------------------------------------
__global__ __launch_bounds__(256, 3) void conv_i8(const signed char* __restrict__ qx,
                                                  const float* __restrict__ invs,
                                                  const signed char* __restrict__ wbuf,
                                                  const float* __restrict__ wm_ptr,
                                                  const float* __restrict__ bias,
                                                  float* __restrict__ out) {
    const int tid = threadIdx.x;
    // bijective XCD swizzle: 8192 blocks % 8 == 0
    const int bid = (blockIdx.x & 7) * 1024 + (blockIdx.x >> 3);
    const int n      = bid >> 9;           // 512 blocks/image
    const int rem    = bid & 511;
    const int rowgrp = rem >> 3;           // 0..63
    const int w0     = (rem & 7) << 5;     // 0..224
    const int wv     = tid >> 6;
    const int gh_out = (rowgrp << 2) + wv; // this wave's output row
    const int lane = tid & 63;
    const int l15 = lane & 15;
    const int lg  = lane >> 4;

    const float wm = wm_ptr[0];

    const signed char* qn = qx + ((size_t)n << 22);          // n * 256*256*64
    const float*       in = invs + ((size_t)n << 16);

    // per-lane clamped cols for nt in {0,1}, dw in {0,1,2}
    int gwc[2][3]; bool cok[2][3];
    #pragma unroll
    for (int nt = 0; nt < 2; ++nt)
        #pragma unroll
        for (int dw = 0; dw < 3; ++dw) {
            const int gw = w0 + nt * 16 + l15 + dw - 1;
            cok[nt][dw] = (gw >= 0) & (gw < XW);
            gwc[nt][dw] = min(max(gw, 0), XW - 1);
        }

    // ---- hoist ALL B fragments + iv scales (independent loads, fully static idx)
    i32x4 B[9][2];
    float IV[9][2];
    #pragma unroll
    for (int dh = 0; dh < 3; ++dh) {
        const int gh = gh_out + dh - 1;
        const bool rok = (gh >= 0) & (gh < XH);
        const int ghc = min(max(gh, 0), XH - 1);
        const signed char* qrow = qn + ((size_t)ghc << 14);   // 256 px * 64 B
        const float*       irow = in + (ghc << 8);
        #pragma unroll
        for (int dw = 0; dw < 3; ++dw) {
            #pragma unroll
            for (int nt = 0; nt < 2; ++nt) {
                const int c = gwc[nt][dw];
                B[dh * 3 + dw][nt] =
                    *reinterpret_cast<const i32x4*>(qrow + (c << 6) + (lg << 4));
                IV[dh * 3 + dw][nt] = (rok & cok[nt][dw]) ? irow[c] : 0.f;
            }
        }
    }

    f32x4 acc[4][2];
    #pragma unroll
    for (int m = 0; m < 4; ++m) {
        acc[m][0] = (f32x4){0.f, 0.f, 0.f, 0.f};
        acc[m][1] = (f32x4){0.f, 0.f, 0.f, 0.f};
    }

    #pragma unroll
    for (int t = 0; t < 9; ++t) {
        #pragma unroll
        for (int m = 0; m < 4; ++m) {
            const i32x4 af = *reinterpret_cast<const i32x4*>(
                wbuf + (((t << 2) + m) << 10) + (lane << 4));
            #pragma unroll
            for (int nt = 0; nt < 2; ++nt) {
                i32x4 tap = __builtin_amdgcn_mfma_i32_16x16x64_i8(
                    af, B[t][nt], (i32x4){0, 0, 0, 0}, 0, 0, 0);
                f32x4 tf;
                tf[0] = (float)tap[0]; tf[1] = (float)tap[1];
                tf[2] = (float)tap[2]; tf[3] = (float)tap[3];
                acc[m][nt] += tf * IV[t][nt];
            }
        }
    }

    // epilogue: D col = l15 (pixel), row = lg*4 + r (out-ch within m-tile)
    #pragma unroll
    for (int m = 0; m < 4; ++m) {
        #pragma unroll
        for (int r = 0; r < 4; ++r) {
            const int o = (m << 4) + (lg << 2) + r;
            const float bz = bias[o];
            float* orow = out + ((((size_t)n << 6) + o) << 16) + (gh_out << 8) + w0;
            orow[l15]      = fmaf(acc[m][0][r], wm, bz);
            orow[16 + l15] = fmaf(acc[m][1][r], wm, bz);
        }
    }
}

// ===========================================================================
// Fallback (round-1, verified): fused bf16 kernel pair, needs ~74 KB of ws.
// ===========================================================================
#define HALO_W 34
#define NPIX 340

__global__ __launch_bounds__(256) void wq_kernel(const float* __restrict__ w,
                                                 float* __restrict__ wm_out,
                                                 u16* __restrict__ wbuf) {
    __shared__ float red[4];
    __shared__ float wm_sh;
    const int tid = threadIdx.x;

    float s = 0.f;
    for (int i = tid; i < XO * XC * 9; i += 256) s += fabsf(w[i]);
    #pragma unroll
    for (int off = 32; off > 0; off >>= 1) s += __shfl_down(s, off, 64);
    if ((tid & 63) == 0) red[tid >> 6] = s;
    __syncthreads();
    if (tid == 0) {
        float tot = red[0] + red[1] + red[2] + red[3];
        float wm = fmaxf(tot / (float)(XO * XC * 9), 1e-5f);
        wm_out[0] = wm;
        wm_sh = wm;
    }
    __syncthreads();
    const float wscale = 1.0f / wm_sh;

    for (int idx = tid; idx < XO * XC * 9; idx += 256) {
        const int j = idx & 7;
        const int l = (idx >> 3) & 63;
        const int c = (idx >> 9) & 1;
        const int m = (idx >> 10) & 3;
        const int t = idx >> 12;
        const int o = m * 16 + (l & 15);
        const int i = c * 32 + (l >> 4) * 8 + j;
        const int kh = t / 3, kw = t % 3;
        const float wv = w[((o * XC + i) * 3 + kh) * 3 + kw];
        const float tern = fminf(fmaxf(rintf(wv * wscale), -1.f), 1.f);
        wbuf[idx] = (u16)(__float_as_uint(tern) >> 16);
    }
}

__global__ __launch_bounds__(256) void conv_kernel(const float* __restrict__ x,
                                                   const u16* __restrict__ wbuf,
                                                   const float* __restrict__ wm_ptr,
                                                   const float* __restrict__ bias,
                                                   float* __restrict__ out) {
    __shared__ __align__(16) u16 q_lds[NPIX * 64];
    __shared__ float invs_lds[NPIX];
    __shared__ float bias_lds[XO];

    const int tid = threadIdx.x;
    const int bid = blockIdx.x;
    const int n   = bid >> 8;
    const int rem = bid & 255;
    const int h0  = (rem >> 3) << 3;
    const int w0  = (rem & 7) << 5;

    if (tid < XO) bias_lds[tid] = bias[tid];

    #pragma unroll 1
    for (int p = tid; p < NPIX; p += 256) {
        const int hr = p / HALO_W;
        const int cl = p - hr * HALO_W;
        const int gh = h0 + hr - 1;
        const int gw = w0 + cl - 1;
        const bool ok = (gh >= 0) & (gh < XH) & (gw >= 0) & (gw < XW);

        float vals[64];
        float amax = 0.f;
        if (ok) {
            const float* px = x + (size_t)n * (XC * CH_STRIDE) + (size_t)gh * XW + gw;
            #pragma unroll
            for (int c = 0; c < 64; ++c) {
                const float v = px[(size_t)c * CH_STRIDE];
                vals[c] = v;
                amax = fmaxf(amax, fabsf(v));
            }
        } else {
            #pragma unroll
            for (int c = 0; c < 64; ++c) vals[c] = 0.f;
        }
        const float am    = fmaxf(amax, 1e-5f);
        const float scale = 127.0f / am;
        invs_lds[p] = ok ? (1.0f / scale) : 0.0f;

        const int sw = (p & 7) << 3;
        #pragma unroll
        for (int cb = 0; cb < 8; ++cb) {
            u16x8 pk;
            #pragma unroll
            for (int j = 0; j < 8; ++j) {
                const float q = fminf(fmaxf(rintf(vals[cb * 8 + j] * scale), -128.f), 127.f);
                pk[j] = (u16)(__float_as_uint(q) >> 16);
            }
            *reinterpret_cast<u16x8*>(&q_lds[p * 64 + ((cb * 8) ^ sw)]) = pk;
        }
    }
    __syncthreads();

    const int lane = tid & 63;
    const int wv   = tid >> 6;
    const int l15  = lane & 15;
    const int lg   = lane >> 4;

    f32x4 acc[4][4];
    #pragma unroll
    for (int m = 0; m < 4; ++m)
        #pragma unroll
        for (int nt = 0; nt < 4; ++nt) acc[m][nt] = (f32x4){0.f, 0.f, 0.f, 0.f};

    const float wm = wm_ptr[0];

    #pragma unroll
    for (int t = 0; t < 9; ++t) {
        const int dh = t / 3, dw = t % 3;

        short8 afr[4][2];
        #pragma unroll
        for (int m = 0; m < 4; ++m)
            #pragma unroll
            for (int c = 0; c < 2; ++c)
                afr[m][c] = *reinterpret_cast<const short8*>(
                    wbuf + ((((t * 4 + m) * 2 + c) * 64 + lane) * 8));

        #pragma unroll
        for (int nt = 0; nt < 4; ++nt) {
            const int rl  = 2 * wv + (nt >> 1);
            const int pix = (rl + dh) * HALO_W + (nt & 1) * 16 + l15 + dw;
            const int sw  = (pix & 7) << 3;
            const u16* qp = &q_lds[pix * 64];
            const short8 b0 = *reinterpret_cast<const short8*>(qp + ((lg * 8) ^ sw));
            const short8 b1 = *reinterpret_cast<const short8*>(qp + ((32 + lg * 8) ^ sw));
            const float  iv = invs_lds[pix];
            #pragma unroll
            for (int m = 0; m < 4; ++m) {
                f32x4 tap = (f32x4){0.f, 0.f, 0.f, 0.f};
                tap = __builtin_amdgcn_mfma_f32_16x16x32_bf16(afr[m][0], b0, tap, 0, 0, 0);
                tap = __builtin_amdgcn_mfma_f32_16x16x32_bf16(afr[m][1], b1, tap, 0, 0, 0);
                acc[m][nt] += tap * iv;
            }
        }
    }

    #pragma unroll
    for (int m = 0; m < 4; ++m) {
        #pragma unroll
        for (int nt = 0; nt < 4; ++nt) {
            const int rl = 2 * wv + (nt >> 1);
            const int gh = h0 + rl;
            const int gw = w0 + (nt & 1) * 16 + l15;
            #pragma unroll
            for (int r = 0; r < 4; ++r) {
                const int o = m * 16 + lg * 4 + r;
                const float v = wm * acc[m][nt][r] + bias_lds[o];
                out[(((size_t)n * XO + o) * XH + gh) * XW + gw] = v;
            }
        }
    }
}

extern "C" void kernel_launch(void* const* d_in, const int* in_sizes, int n_in,
                              void* d_out, int out_size, void* d_ws, size_t ws_size,
                              hipStream_t stream) {
    const float* x    = (const float*)d_in[0];
    const float* w    = (const float*)d_in[1];
    const float* bias = (const float*)d_in[2];
    float* out = (float*)d_out;

    if (ws_size >= (size_t)WS_NEED) {
        signed char* qx       = (signed char*)d_ws;
        float*       invsb    = (float*)((char*)d_ws + INVS_OFF);
        signed char* wbuf     = (signed char*)((char*)d_ws + WBUF_OFF);
        float*       partials = (float*)((char*)d_ws + PART_OFF);
        float*       wm       = (float*)((char*)d_ws + WM_OFF);

        wq_reduce<<<64, 256, 0, stream>>>(w, partials);
        wq_tern_i8<<<144, 256, 0, stream>>>(w, partials, wm, wbuf);
        aq_i8<<<XN * 256, 256, 0, stream>>>(x, qx, invsb);
        conv_i8<<<XN * 512, 256, 0, stream>>>(qx, invsb, wbuf, wm, bias, out);
    } else {
        float* wsf  = (float*)d_ws;
        u16*   wbuf = (u16*)((char*)d_ws + 64);
        wq_kernel<<<1, 256, 0, stream>>>(w, wsf, wbuf);
        conv_kernel<<<XN * 256, 256, 0, stream>>>(x, wbuf, wsf, bias, out);
    }
}

// Round 6
// 195.801 us; speedup vs baseline: 1.7327x; 1.3706x over previous
//
#include <hip/hip_runtime.h>
#include <hip/hip_bf16.h>

typedef __attribute__((ext_vector_type(8))) short short8;
typedef __attribute__((ext_vector_type(4))) float f32x4;
typedef __attribute__((ext_vector_type(4))) int i32x4;
typedef unsigned short u16;
typedef unsigned int u32;
typedef __attribute__((ext_vector_type(8))) unsigned short u16x8;
typedef __attribute__((ext_vector_type(4))) u32 u32x4;

#define XN 16
#define XC 64
#define XH 256
#define XW 256
#define XO 64
#define CH_STRIDE (XH * XW)   // 65536

// ---- i8 path ws layout (bytes) ----
#define QX_OFF    0                         // i8[16*256*256*64] = 67,108,864 (pixel-major NHWC)
#define INVS_OFF  67108864                  // f32[1048576] = 4,194,304
#define WBUF_OFF  71303168                  // i8[36864]
#define PART_OFF  71340032                  // f32[64]
#define WM_OFF    71340288                  // f32[1]
#define WS_NEED   71340544

// ---------------------------------------------------------------------------
// Weight quant stage 1: deterministic partial |w| sums (64 blocks x 576 elems).
// ---------------------------------------------------------------------------
__global__ __launch_bounds__(256) void wq_reduce(const float* __restrict__ w,
                                                 float* __restrict__ partials) {
    __shared__ float red[4];
    const int tid = threadIdx.x;
    const int base = blockIdx.x * 576;       // 36864 / 64
    float s = 0.f;
    for (int i = tid; i < 576; i += 256) s += fabsf(w[base + i]);
    #pragma unroll
    for (int off = 32; off > 0; off >>= 1) s += __shfl_down(s, off, 64);
    if ((tid & 63) == 0) red[tid >> 6] = s;
    __syncthreads();
    if (tid == 0) partials[blockIdx.x] = red[0] + red[1] + red[2] + red[3];
}

// ---------------------------------------------------------------------------
// Weight quant stage 2: ternarize to i8 in MFMA A-fragment layout (144 blocks).
//   idx = ((t*4 + m)*64 + l)*16 + j
//   holds tern[o = m*16 + (l&15)][i = (l>>4)*16 + j]  for tap t
// ---------------------------------------------------------------------------
__global__ __launch_bounds__(256) void wq_tern_i8(const float* __restrict__ w,
                                                  const float* __restrict__ partials,
                                                  float* __restrict__ wm_out,
                                                  signed char* __restrict__ wbuf) {
    __shared__ float wm_sh;
    const int tid = threadIdx.x;
    if (tid == 0) {
        float tot = 0.f;
        #pragma unroll
        for (int i = 0; i < 64; ++i) tot += partials[i];   // fixed order: deterministic
        float wm = fmaxf(tot / (float)(XO * XC * 9), 1e-5f);
        wm_sh = wm;
        if (blockIdx.x == 0) wm_out[0] = wm;
    }
    __syncthreads();
    const float wscale = 1.0f / wm_sh;

    const int idx = blockIdx.x * 256 + tid;  // < 36864
    const int j = idx & 15;
    const int l = (idx >> 4) & 63;
    const int m = (idx >> 10) & 3;
    const int t = idx >> 12;                 // 0..8
    const int o = m * 16 + (l & 15);
    const int i = (l >> 4) * 16 + j;
    const int kh = t / 3, kw = t % 3;
    const float wv = w[((o * XC + i) * 3 + kh) * 3 + kw];
    const float tern = fminf(fmaxf(rintf(wv * wscale), -1.f), 1.f);
    wbuf[idx] = (signed char)(int)tern;
}

// ---------------------------------------------------------------------------
// Activation quant: one block per (n,h) row. qx = i8, pixel-major (64 B/px,
// channels contiguous, NO swizzle). invs = amax/127 per pixel.
// ---------------------------------------------------------------------------
__global__ __launch_bounds__(256) void aq_i8(const float* __restrict__ x,
                                             signed char* __restrict__ qx,
                                             float* __restrict__ invs) {
    const int tid = threadIdx.x;
    const int b = blockIdx.x;            // 4096 = 16*256
    const int n = b >> 8;

    const float* px = x + ((size_t)n << 22) + ((size_t)(b & 255) << 8) + tid;
    float vals[64];
    float amax = 0.f;
    #pragma unroll
    for (int c = 0; c < 64; ++c) {
        const float v = px[(size_t)c << 16];
        vals[c] = v;
        amax = fmaxf(amax, fabsf(v));
    }
    const float am = fmaxf(amax, 1e-5f);
    const float scale = 127.0f / am;
    invs[((size_t)b << 8) + tid] = am * (1.0f / 127.0f);

    // pack 64 quantized ints into 16 words, write as 4x16B (contiguous per thread)
    u32 words[16];
    #pragma unroll
    for (int wk = 0; wk < 16; ++wk) {
        u32 acc = 0;
        #pragma unroll
        for (int bb = 0; bb < 4; ++bb) {
            const float q = fminf(fmaxf(rintf(vals[wk * 4 + bb] * scale), -128.f), 127.f);
            acc |= ((u32)((int)q) & 255u) << (bb * 8);
        }
        words[wk] = acc;
    }
    u32* dst = (u32*)(qx + ((((size_t)b << 8) + tid) << 6));
    #pragma unroll
    for (int i = 0; i < 4; ++i) {
        *reinterpret_cast<u32x4*>(dst + i * 4) =
            (u32x4){words[i * 4], words[i * 4 + 1], words[i * 4 + 2], words[i * 4 + 3]};
    }
}

// ---------------------------------------------------------------------------
// Conv v3: no LDS, no barriers. Wave = 1 output row x 32 px x 64 out-ch.
// ALL 18 B-fragments + 18 iv scalars loaded, then sched_barrier(0) pins them
// ABOVE the MFMA chain (compiler cannot sink the loads back to their uses ->
// one latency exposure for ~54 outstanding VMEM ops). A-fragments (36 KB,
// L1/L2-resident) load inside the unrolled tap loop. wm folded into epilogue.
// Nontemporal stores: discriminate the 1.5x WRITE_SIZE amplification.
// ---------------------------------------------------------------------------
__global__ __launch_bounds__(256, 3) void conv_i8(const signed char* __restrict__ qx,
                                                  const float* __restrict__ invs,
                                                  const signed char* __restrict__ wbuf,
                                                  const float* __restrict__ wm_ptr,
                                                  const float* __restrict__ bias,
                                                  float* __restrict__ out) {
    const int tid = threadIdx.x;
    // bijective XCD swizzle: 8192 blocks % 8 == 0
    const int bid = (blockIdx.x & 7) * 1024 + (blockIdx.x >> 3);
    const int n      = bid >> 9;           // 512 blocks/image
    const int rem    = bid & 511;
    const int rowgrp = rem >> 3;           // 0..63
    const int w0     = (rem & 7) << 5;     // 0..224
    const int wv     = tid >> 6;
    const int gh_out = (rowgrp << 2) + wv; // this wave's output row
    const int lane = tid & 63;
    const int l15 = lane & 15;
    const int lg  = lane >> 4;

    const float wm = wm_ptr[0];

    const signed char* qn = qx + ((size_t)n << 22);          // n * 256*256*64
    const float*       in = invs + ((size_t)n << 16);

    // per-lane clamped cols for nt in {0,1}, dw in {0,1,2}
    int gwc[2][3]; bool cok[2][3];
    #pragma unroll
    for (int nt = 0; nt < 2; ++nt)
        #pragma unroll
        for (int dw = 0; dw < 3; ++dw) {
            const int gw = w0 + nt * 16 + l15 + dw - 1;
            cok[nt][dw] = (gw >= 0) & (gw < XW);
            gwc[nt][dw] = min(max(gw, 0), XW - 1);
        }

    // ---- load ALL B fragments + iv scales (independent, fully static idx) ----
    i32x4 B[9][2];
    float IV[9][2];
    #pragma unroll
    for (int dh = 0; dh < 3; ++dh) {
        const int gh = gh_out + dh - 1;
        const bool rok = (gh >= 0) & (gh < XH);
        const int ghc = min(max(gh, 0), XH - 1);
        const signed char* qrow = qn + ((size_t)ghc << 14);   // 256 px * 64 B
        const float*       irow = in + (ghc << 8);
        #pragma unroll
        for (int dw = 0; dw < 3; ++dw) {
            #pragma unroll
            for (int nt = 0; nt < 2; ++nt) {
                const int c = gwc[nt][dw];
                B[dh * 3 + dw][nt] =
                    *reinterpret_cast<const i32x4*>(qrow + (c << 6) + (lg << 4));
                IV[dh * 3 + dw][nt] = (rok & cok[nt][dw]) ? irow[c] : 0.f;
            }
        }
    }
    // pin: loads above, MFMA chain below — compiler cannot sink the loads
    __builtin_amdgcn_sched_barrier(0);

    f32x4 acc[4][2];
    #pragma unroll
    for (int m = 0; m < 4; ++m) {
        acc[m][0] = (f32x4){0.f, 0.f, 0.f, 0.f};
        acc[m][1] = (f32x4){0.f, 0.f, 0.f, 0.f};
    }

    #pragma unroll
    for (int t = 0; t < 9; ++t) {
        #pragma unroll
        for (int m = 0; m < 4; ++m) {
            const i32x4 af = *reinterpret_cast<const i32x4*>(
                wbuf + (((t << 2) + m) << 10) + (lane << 4));
            #pragma unroll
            for (int nt = 0; nt < 2; ++nt) {
                i32x4 tap = __builtin_amdgcn_mfma_i32_16x16x64_i8(
                    af, B[t][nt], (i32x4){0, 0, 0, 0}, 0, 0, 0);
                f32x4 tf;
                tf[0] = (float)tap[0]; tf[1] = (float)tap[1];
                tf[2] = (float)tap[2]; tf[3] = (float)tap[3];
                acc[m][nt] += tf * IV[t][nt];
            }
        }
    }

    // epilogue: D col = l15 (pixel), row = lg*4 + r (out-ch within m-tile)
    #pragma unroll
    for (int m = 0; m < 4; ++m) {
        #pragma unroll
        for (int r = 0; r < 4; ++r) {
            const int o = (m << 4) + (lg << 2) + r;
            const float bz = bias[o];
            float* orow = out + ((((size_t)n << 6) + o) << 16) + (gh_out << 8) + w0;
            __builtin_nontemporal_store(fmaf(acc[m][0][r], wm, bz), orow + l15);
            __builtin_nontemporal_store(fmaf(acc[m][1][r], wm, bz), orow + 16 + l15);
        }
    }
}

// ===========================================================================
// Fallback (round-1, verified): fused bf16 kernel pair, needs ~74 KB of ws.
// ===========================================================================
#define HALO_W 34
#define NPIX 340

__global__ __launch_bounds__(256) void wq_kernel(const float* __restrict__ w,
                                                 float* __restrict__ wm_out,
                                                 u16* __restrict__ wbuf) {
    __shared__ float red[4];
    __shared__ float wm_sh;
    const int tid = threadIdx.x;

    float s = 0.f;
    for (int i = tid; i < XO * XC * 9; i += 256) s += fabsf(w[i]);
    #pragma unroll
    for (int off = 32; off > 0; off >>= 1) s += __shfl_down(s, off, 64);
    if ((tid & 63) == 0) red[tid >> 6] = s;
    __syncthreads();
    if (tid == 0) {
        float tot = red[0] + red[1] + red[2] + red[3];
        float wm = fmaxf(tot / (float)(XO * XC * 9), 1e-5f);
        wm_out[0] = wm;
        wm_sh = wm;
    }
    __syncthreads();
    const float wscale = 1.0f / wm_sh;

    for (int idx = tid; idx < XO * XC * 9; idx += 256) {
        const int j = idx & 7;
        const int l = (idx >> 3) & 63;
        const int c = (idx >> 9) & 1;
        const int m = (idx >> 10) & 3;
        const int t = idx >> 12;
        const int o = m * 16 + (l & 15);
        const int i = c * 32 + (l >> 4) * 8 + j;
        const int kh = t / 3, kw = t % 3;
        const float wv = w[((o * XC + i) * 3 + kh) * 3 + kw];
        const float tern = fminf(fmaxf(rintf(wv * wscale), -1.f), 1.f);
        wbuf[idx] = (u16)(__float_as_uint(tern) >> 16);
    }
}

__global__ __launch_bounds__(256) void conv_kernel(const float* __restrict__ x,
                                                   const u16* __restrict__ wbuf,
                                                   const float* __restrict__ wm_ptr,
                                                   const float* __restrict__ bias,
                                                   float* __restrict__ out) {
    __shared__ __align__(16) u16 q_lds[NPIX * 64];
    __shared__ float invs_lds[NPIX];
    __shared__ float bias_lds[XO];

    const int tid = threadIdx.x;
    const int bid = blockIdx.x;
    const int n   = bid >> 8;
    const int rem = bid & 255;
    const int h0  = (rem >> 3) << 3;
    const int w0  = (rem & 7) << 5;

    if (tid < XO) bias_lds[tid] = bias[tid];

    #pragma unroll 1
    for (int p = tid; p < NPIX; p += 256) {
        const int hr = p / HALO_W;
        const int cl = p - hr * HALO_W;
        const int gh = h0 + hr - 1;
        const int gw = w0 + cl - 1;
        const bool ok = (gh >= 0) & (gh < XH) & (gw >= 0) & (gw < XW);

        float vals[64];
        float amax = 0.f;
        if (ok) {
            const float* px = x + (size_t)n * (XC * CH_STRIDE) + (size_t)gh * XW + gw;
            #pragma unroll
            for (int c = 0; c < 64; ++c) {
                const float v = px[(size_t)c * CH_STRIDE];
                vals[c] = v;
                amax = fmaxf(amax, fabsf(v));
            }
        } else {
            #pragma unroll
            for (int c = 0; c < 64; ++c) vals[c] = 0.f;
        }
        const float am    = fmaxf(amax, 1e-5f);
        const float scale = 127.0f / am;
        invs_lds[p] = ok ? (1.0f / scale) : 0.0f;

        const int sw = (p & 7) << 3;
        #pragma unroll
        for (int cb = 0; cb < 8; ++cb) {
            u16x8 pk;
            #pragma unroll
            for (int j = 0; j < 8; ++j) {
                const float q = fminf(fmaxf(rintf(vals[cb * 8 + j] * scale), -128.f), 127.f);
                pk[j] = (u16)(__float_as_uint(q) >> 16);
            }
            *reinterpret_cast<u16x8*>(&q_lds[p * 64 + ((cb * 8) ^ sw)]) = pk;
        }
    }
    __syncthreads();

    const int lane = tid & 63;
    const int wv   = tid >> 6;
    const int l15  = lane & 15;
    const int lg   = lane >> 4;

    f32x4 acc[4][4];
    #pragma unroll
    for (int m = 0; m < 4; ++m)
        #pragma unroll
        for (int nt = 0; nt < 4; ++nt) acc[m][nt] = (f32x4){0.f, 0.f, 0.f, 0.f};

    const float wm = wm_ptr[0];

    #pragma unroll
    for (int t = 0; t < 9; ++t) {
        const int dh = t / 3, dw = t % 3;

        short8 afr[4][2];
        #pragma unroll
        for (int m = 0; m < 4; ++m)
            #pragma unroll
            for (int c = 0; c < 2; ++c)
                afr[m][c] = *reinterpret_cast<const short8*>(
                    wbuf + ((((t * 4 + m) * 2 + c) * 64 + lane) * 8));

        #pragma unroll
        for (int nt = 0; nt < 4; ++nt) {
            const int rl  = 2 * wv + (nt >> 1);
            const int pix = (rl + dh) * HALO_W + (nt & 1) * 16 + l15 + dw;
            const int sw  = (pix & 7) << 3;
            const u16* qp = &q_lds[pix * 64];
            const short8 b0 = *reinterpret_cast<const short8*>(qp + ((lg * 8) ^ sw));
            const short8 b1 = *reinterpret_cast<const short8*>(qp + ((32 + lg * 8) ^ sw));
            const float  iv = invs_lds[pix];
            #pragma unroll
            for (int m = 0; m < 4; ++m) {
                f32x4 tap = (f32x4){0.f, 0.f, 0.f, 0.f};
                tap = __builtin_amdgcn_mfma_f32_16x16x32_bf16(afr[m][0], b0, tap, 0, 0, 0);
                tap = __builtin_amdgcn_mfma_f32_16x16x32_bf16(afr[m][1], b1, tap, 0, 0, 0);
                acc[m][nt] += tap * iv;
            }
        }
    }

    #pragma unroll
    for (int m = 0; m < 4; ++m) {
        #pragma unroll
        for (int nt = 0; nt < 4; ++nt) {
            const int rl = 2 * wv + (nt >> 1);
            const int gh = h0 + rl;
            const int gw = w0 + (nt & 1) * 16 + l15;
            #pragma unroll
            for (int r = 0; r < 4; ++r) {
                const int o = m * 16 + lg * 4 + r;
                const float v = wm * acc[m][nt][r] + bias_lds[o];
                out[(((size_t)n * XO + o) * XH + gh) * XW + gw] = v;
            }
        }
    }
}

extern "C" void kernel_launch(void* const* d_in, const int* in_sizes, int n_in,
                              void* d_out, int out_size, void* d_ws, size_t ws_size,
                              hipStream_t stream) {
    const float* x    = (const float*)d_in[0];
    const float* w    = (const float*)d_in[1];
    const float* bias = (const float*)d_in[2];
    float* out = (float*)d_out;

    if (ws_size >= (size_t)WS_NEED) {
        signed char* qx       = (signed char*)d_ws;
        float*       invsb    = (float*)((char*)d_ws + INVS_OFF);
        signed char* wbuf     = (signed char*)((char*)d_ws + WBUF_OFF);
        float*       partials = (float*)((char*)d_ws + PART_OFF);
        float*       wm       = (float*)((char*)d_ws + WM_OFF);

        wq_reduce<<<64, 256, 0, stream>>>(w, partials);
        wq_tern_i8<<<144, 256, 0, stream>>>(w, partials, wm, wbuf);
        aq_i8<<<XN * 256, 256, 0, stream>>>(x, qx, invsb);
        conv_i8<<<XN * 512, 256, 0, stream>>>(qx, invsb, wbuf, wm, bias, out);
    } else {
        float* wsf  = (float*)d_ws;
        u16*   wbuf = (u16*)((char*)d_ws + 64);
        wq_kernel<<<1, 256, 0, stream>>>(w, wsf, wbuf);
        conv_kernel<<<XN * 256, 256, 0, stream>>>(x, wbuf, wsf, bias, out);
    }
}

// Round 7
// 165.160 us; speedup vs baseline: 2.0542x; 1.1855x over previous
//
#include <hip/hip_runtime.h>
#include <hip/hip_bf16.h>

typedef __attribute__((ext_vector_type(8))) short short8;
typedef __attribute__((ext_vector_type(4))) float f32x4;
typedef __attribute__((ext_vector_type(4))) int i32x4;
typedef unsigned short u16;
typedef unsigned int u32;
typedef __attribute__((ext_vector_type(8))) unsigned short u16x8;
typedef __attribute__((ext_vector_type(4))) u32 u32x4;

#define XN 16
#define XC 64
#define XH 256
#define XW 256
#define XO 64
#define CH_STRIDE (XH * XW)   // 65536

// ---- i8 path ws layout (bytes) ----
#define QX_OFF    0                         // i8[16*256*256*64] = 67,108,864 (pixel-major NHWC)
#define INVS_OFF  67108864                  // f32[1048576] = 4,194,304
#define WBUF_OFF  71303168                  // i8[36864]
#define PART_OFF  71340032                  // f32[64]
#define WM_OFF    71340288                  // f32[1]
#define WS_NEED   71340544

// ---------------------------------------------------------------------------
// Weight quant stage 1: deterministic partial |w| sums (64 blocks x 576 elems).
// ---------------------------------------------------------------------------
__global__ __launch_bounds__(256) void wq_reduce(const float* __restrict__ w,
                                                 float* __restrict__ partials) {
    __shared__ float red[4];
    const int tid = threadIdx.x;
    const int base = blockIdx.x * 576;       // 36864 / 64
    float s = 0.f;
    for (int i = tid; i < 576; i += 256) s += fabsf(w[base + i]);
    #pragma unroll
    for (int off = 32; off > 0; off >>= 1) s += __shfl_down(s, off, 64);
    if ((tid & 63) == 0) red[tid >> 6] = s;
    __syncthreads();
    if (tid == 0) partials[blockIdx.x] = red[0] + red[1] + red[2] + red[3];
}

// ---------------------------------------------------------------------------
// Weight quant stage 2: ternarize to i8 in MFMA A-fragment layout (144 blocks).
//   idx = ((t*4 + m)*64 + l)*16 + j
//   holds tern[o = m*16 + (l&15)][i = (l>>4)*16 + j]  for tap t
// ---------------------------------------------------------------------------
__global__ __launch_bounds__(256) void wq_tern_i8(const float* __restrict__ w,
                                                  const float* __restrict__ partials,
                                                  float* __restrict__ wm_out,
                                                  signed char* __restrict__ wbuf) {
    __shared__ float wm_sh;
    const int tid = threadIdx.x;
    if (tid == 0) {
        float tot = 0.f;
        #pragma unroll
        for (int i = 0; i < 64; ++i) tot += partials[i];   // fixed order: deterministic
        float wm = fmaxf(tot / (float)(XO * XC * 9), 1e-5f);
        wm_sh = wm;
        if (blockIdx.x == 0) wm_out[0] = wm;
    }
    __syncthreads();
    const float wscale = 1.0f / wm_sh;

    const int idx = blockIdx.x * 256 + tid;  // < 36864
    const int j = idx & 15;
    const int l = (idx >> 4) & 63;
    const int m = (idx >> 10) & 3;
    const int t = idx >> 12;                 // 0..8
    const int o = m * 16 + (l & 15);
    const int i = (l >> 4) * 16 + j;
    const int kh = t / 3, kw = t % 3;
    const float wv = w[((o * XC + i) * 3 + kh) * 3 + kw];
    const float tern = fminf(fmaxf(rintf(wv * wscale), -1.f), 1.f);
    wbuf[idx] = (signed char)(int)tern;
}

// ---------------------------------------------------------------------------
// Activation quant: one block per (n,h) row. qx = i8, pixel-major (64 B/px,
// channels contiguous, NO swizzle). invs = amax/127 per pixel.
// ---------------------------------------------------------------------------
__global__ __launch_bounds__(256) void aq_i8(const float* __restrict__ x,
                                             signed char* __restrict__ qx,
                                             float* __restrict__ invs) {
    const int tid = threadIdx.x;
    const int b = blockIdx.x;            // 4096 = 16*256
    const int n = b >> 8;

    const float* px = x + ((size_t)n << 22) + ((size_t)(b & 255) << 8) + tid;
    float vals[64];
    float amax = 0.f;
    #pragma unroll
    for (int c = 0; c < 64; ++c) {
        const float v = px[(size_t)c << 16];
        vals[c] = v;
        amax = fmaxf(amax, fabsf(v));
    }
    const float am = fmaxf(amax, 1e-5f);
    const float scale = 127.0f / am;
    invs[((size_t)b << 8) + tid] = am * (1.0f / 127.0f);

    // pack 64 quantized ints into 16 words, write as 4x16B (contiguous per thread)
    u32 words[16];
    #pragma unroll
    for (int wk = 0; wk < 16; ++wk) {
        u32 acc = 0;
        #pragma unroll
        for (int bb = 0; bb < 4; ++bb) {
            const float q = fminf(fmaxf(rintf(vals[wk * 4 + bb] * scale), -128.f), 127.f);
            acc |= ((u32)((int)q) & 255u) << (bb * 8);
        }
        words[wk] = acc;
    }
    u32* dst = (u32*)(qx + ((((size_t)b << 8) + tid) << 6));
    #pragma unroll
    for (int i = 0; i < 4; ++i) {
        *reinterpret_cast<u32x4*>(dst + i * 4) =
            (u32x4){words[i * 4], words[i * 4 + 1], words[i * 4 + 2], words[i * 4 + 3]};
    }
}

// ---------------------------------------------------------------------------
// Conv v4: wave = 2 output rows x 32 px x 64 out-ch (4-row B window, 24 B
// fragments feed 144 MFMAs). All B/IV loads pinned live via empty inline-asm
// (forces simultaneous liveness -> single latency exposure), sched_barrier(0)
// keeps them above the MFMA chain. Epilogue: acc -> per-wave LDS [64][36]
// (pad 36: conflict-free, 16B-aligned rows) -> lane=(channel,4px) readback ->
// nontemporal f32x4 stores where each 8-lane group covers a FULL 128B line
// (kills the 1.45x partial-line write amplification).
// ---------------------------------------------------------------------------
__global__ __launch_bounds__(256, 2) void conv_i8(const signed char* __restrict__ qx,
                                                  const float* __restrict__ invs,
                                                  const signed char* __restrict__ wbuf,
                                                  const float* __restrict__ wm_ptr,
                                                  const float* __restrict__ bias,
                                                  float* __restrict__ out) {
    __shared__ float eplds[4][2][64][36];   // 73,728 B; per-wave private regions

    const int tid = threadIdx.x;
    // bijective XCD swizzle: 4096 blocks, 512 per XCD
    const int bid = (blockIdx.x & 7) * 512 + (blockIdx.x >> 3);
    const int n      = bid >> 8;           // 256 blocks/image
    const int rem    = bid & 255;
    const int rowgrp = rem >> 3;           // 0..31 (8 rows each)
    const int w0     = (rem & 7) << 5;     // 0..224
    const int wv     = tid >> 6;
    const int gh0    = (rowgrp << 3) + (wv << 1);  // wave's first output row
    const int lane = tid & 63;
    const int l15 = lane & 15;
    const int lg  = lane >> 4;

    const signed char* qn = qx + ((size_t)n << 22);          // n * 256*256*64
    const float*       in = invs + ((size_t)n << 16);

    // per-lane clamped cols for nt in {0,1}, dw in {0,1,2}
    int gwc[2][3]; bool cok[2][3];
    #pragma unroll
    for (int nt = 0; nt < 2; ++nt)
        #pragma unroll
        for (int dw = 0; dw < 3; ++dw) {
            const int gw = w0 + nt * 16 + l15 + dw - 1;
            cok[nt][dw] = (gw >= 0) & (gw < XW);
            gwc[nt][dw] = min(max(gw, 0), XW - 1);
        }

    // ---- load ALL 24 B fragments + 24 iv scales (4 window rows) ----
    i32x4 B[4][3][2];
    float IV[4][3][2];
    #pragma unroll
    for (int w = 0; w < 4; ++w) {
        const int gh = gh0 + w - 1;
        const bool rok = (gh >= 0) & (gh < XH);
        const int ghc = min(max(gh, 0), XH - 1);
        const signed char* qrow = qn + ((size_t)ghc << 14);   // 256 px * 64 B
        const float*       irow = in + (ghc << 8);
        #pragma unroll
        for (int dw = 0; dw < 3; ++dw) {
            #pragma unroll
            for (int nt = 0; nt < 2; ++nt) {
                const int c = gwc[nt][dw];
                B[w][dw][nt] = *reinterpret_cast<const i32x4*>(qrow + (c << 6) + (lg << 4));
                IV[w][dw][nt] = (rok & cok[nt][dw]) ? irow[c] : 0.f;
            }
        }
    }
    // force simultaneous liveness of every fragment (compiler cannot sink/reuse)
    #pragma unroll
    for (int w = 0; w < 4; ++w)
        #pragma unroll
        for (int dw = 0; dw < 3; ++dw)
            #pragma unroll
            for (int nt = 0; nt < 2; ++nt) {
                asm volatile("" : "+v"(B[w][dw][nt]));
                asm volatile("" : "+v"(IV[w][dw][nt]));
            }
    __builtin_amdgcn_sched_barrier(0);

    f32x4 acc[2][4][2];
    #pragma unroll
    for (int ri = 0; ri < 2; ++ri)
        #pragma unroll
        for (int m = 0; m < 4; ++m)
            #pragma unroll
            for (int nt = 0; nt < 2; ++nt)
                acc[ri][m][nt] = (f32x4){0.f, 0.f, 0.f, 0.f};

    #pragma unroll
    for (int dh = 0; dh < 3; ++dh) {
        #pragma unroll
        for (int dw = 0; dw < 3; ++dw) {
            const int t = dh * 3 + dw;
            #pragma unroll
            for (int m = 0; m < 4; ++m) {
                const i32x4 af = *reinterpret_cast<const i32x4*>(
                    wbuf + (((t << 2) + m) << 10) + (lane << 4));
                #pragma unroll
                for (int ri = 0; ri < 2; ++ri) {
                    const int w = ri + dh;
                    #pragma unroll
                    for (int nt = 0; nt < 2; ++nt) {
                        i32x4 tap = __builtin_amdgcn_mfma_i32_16x16x64_i8(
                            af, B[w][dw][nt], (i32x4){0, 0, 0, 0}, 0, 0, 0);
                        f32x4 tf;
                        tf[0] = (float)tap[0]; tf[1] = (float)tap[1];
                        tf[2] = (float)tap[2]; tf[3] = (float)tap[3];
                        acc[ri][m][nt] += tf * IV[w][dw][nt];
                    }
                }
            }
        }
    }

    // ---- epilogue: acc -> LDS (wm+bias folded) -> full-128B-line NT stores ----
    const float wm = wm_ptr[0];
    float bias_v[4][4];
    #pragma unroll
    for (int m = 0; m < 4; ++m)
        #pragma unroll
        for (int r = 0; r < 4; ++r)
            bias_v[m][r] = bias[(m << 4) + (lg << 2) + r];

    #pragma unroll
    for (int ri = 0; ri < 2; ++ri)
        #pragma unroll
        for (int m = 0; m < 4; ++m)
            #pragma unroll
            for (int nt = 0; nt < 2; ++nt)
                #pragma unroll
                for (int r = 0; r < 4; ++r)
                    eplds[wv][ri][(m << 4) + (lg << 2) + r][(nt << 4) + l15] =
                        fmaf(acc[ri][m][nt][r], wm, bias_v[m][r]);

    // same-wave LDS readback (no barrier needed; lgkmcnt handled by compiler)
    #pragma unroll
    for (int ri = 0; ri < 2; ++ri) {
        const int gh = gh0 + ri;
        #pragma unroll
        for (int j = 0; j < 8; ++j) {
            const int o   = (j << 3) + (lane >> 3);
            const int px0 = (lane & 7) << 2;
            const f32x4 v = *reinterpret_cast<const f32x4*>(&eplds[wv][ri][o][px0]);
            float* dst = out + ((((size_t)n << 6) + o) << 16) + (gh << 8) + w0 + px0;
            __builtin_nontemporal_store(v, reinterpret_cast<f32x4*>(dst));
        }
    }
}

// ===========================================================================
// Fallback (round-1, verified): fused bf16 kernel pair, needs ~74 KB of ws.
// ===========================================================================
#define HALO_W 34
#define NPIX 340

__global__ __launch_bounds__(256) void wq_kernel(const float* __restrict__ w,
                                                 float* __restrict__ wm_out,
                                                 u16* __restrict__ wbuf) {
    __shared__ float red[4];
    __shared__ float wm_sh;
    const int tid = threadIdx.x;

    float s = 0.f;
    for (int i = tid; i < XO * XC * 9; i += 256) s += fabsf(w[i]);
    #pragma unroll
    for (int off = 32; off > 0; off >>= 1) s += __shfl_down(s, off, 64);
    if ((tid & 63) == 0) red[tid >> 6] = s;
    __syncthreads();
    if (tid == 0) {
        float tot = red[0] + red[1] + red[2] + red[3];
        float wm = fmaxf(tot / (float)(XO * XC * 9), 1e-5f);
        wm_out[0] = wm;
        wm_sh = wm;
    }
    __syncthreads();
    const float wscale = 1.0f / wm_sh;

    for (int idx = tid; idx < XO * XC * 9; idx += 256) {
        const int j = idx & 7;
        const int l = (idx >> 3) & 63;
        const int c = (idx >> 9) & 1;
        const int m = (idx >> 10) & 3;
        const int t = idx >> 12;
        const int o = m * 16 + (l & 15);
        const int i = c * 32 + (l >> 4) * 8 + j;
        const int kh = t / 3, kw = t % 3;
        const float wv = w[((o * XC + i) * 3 + kh) * 3 + kw];
        const float tern = fminf(fmaxf(rintf(wv * wscale), -1.f), 1.f);
        wbuf[idx] = (u16)(__float_as_uint(tern) >> 16);
    }
}

__global__ __launch_bounds__(256) void conv_kernel(const float* __restrict__ x,
                                                   const u16* __restrict__ wbuf,
                                                   const float* __restrict__ wm_ptr,
                                                   const float* __restrict__ bias,
                                                   float* __restrict__ out) {
    __shared__ __align__(16) u16 q_lds[NPIX * 64];
    __shared__ float invs_lds[NPIX];
    __shared__ float bias_lds[XO];

    const int tid = threadIdx.x;
    const int bid = blockIdx.x;
    const int n   = bid >> 8;
    const int rem = bid & 255;
    const int h0  = (rem >> 3) << 3;
    const int w0  = (rem & 7) << 5;

    if (tid < XO) bias_lds[tid] = bias[tid];

    #pragma unroll 1
    for (int p = tid; p < NPIX; p += 256) {
        const int hr = p / HALO_W;
        const int cl = p - hr * HALO_W;
        const int gh = h0 + hr - 1;
        const int gw = w0 + cl - 1;
        const bool ok = (gh >= 0) & (gh < XH) & (gw >= 0) & (gw < XW);

        float vals[64];
        float amax = 0.f;
        if (ok) {
            const float* px = x + (size_t)n * (XC * CH_STRIDE) + (size_t)gh * XW + gw;
            #pragma unroll
            for (int c = 0; c < 64; ++c) {
                const float v = px[(size_t)c * CH_STRIDE];
                vals[c] = v;
                amax = fmaxf(amax, fabsf(v));
            }
        } else {
            #pragma unroll
            for (int c = 0; c < 64; ++c) vals[c] = 0.f;
        }
        const float am    = fmaxf(amax, 1e-5f);
        const float scale = 127.0f / am;
        invs_lds[p] = ok ? (1.0f / scale) : 0.0f;

        const int sw = (p & 7) << 3;
        #pragma unroll
        for (int cb = 0; cb < 8; ++cb) {
            u16x8 pk;
            #pragma unroll
            for (int j = 0; j < 8; ++j) {
                const float q = fminf(fmaxf(rintf(vals[cb * 8 + j] * scale), -128.f), 127.f);
                pk[j] = (u16)(__float_as_uint(q) >> 16);
            }
            *reinterpret_cast<u16x8*>(&q_lds[p * 64 + ((cb * 8) ^ sw)]) = pk;
        }
    }
    __syncthreads();

    const int lane = tid & 63;
    const int wv   = tid >> 6;
    const int l15  = lane & 15;
    const int lg   = lane >> 4;

    f32x4 acc[4][4];
    #pragma unroll
    for (int m = 0; m < 4; ++m)
        #pragma unroll
        for (int nt = 0; nt < 4; ++nt) acc[m][nt] = (f32x4){0.f, 0.f, 0.f, 0.f};

    const float wm = wm_ptr[0];

    #pragma unroll
    for (int t = 0; t < 9; ++t) {
        const int dh = t / 3, dw = t % 3;

        short8 afr[4][2];
        #pragma unroll
        for (int m = 0; m < 4; ++m)
            #pragma unroll
            for (int c = 0; c < 2; ++c)
                afr[m][c] = *reinterpret_cast<const short8*>(
                    wbuf + ((((t * 4 + m) * 2 + c) * 64 + lane) * 8));

        #pragma unroll
        for (int nt = 0; nt < 4; ++nt) {
            const int rl  = 2 * wv + (nt >> 1);
            const int pix = (rl + dh) * HALO_W + (nt & 1) * 16 + l15 + dw;
            const int sw  = (pix & 7) << 3;
            const u16* qp = &q_lds[pix * 64];
            const short8 b0 = *reinterpret_cast<const short8*>(qp + ((lg * 8) ^ sw));
            const short8 b1 = *reinterpret_cast<const short8*>(qp + ((32 + lg * 8) ^ sw));
            const float  iv = invs_lds[pix];
            #pragma unroll
            for (int m = 0; m < 4; ++m) {
                f32x4 tap = (f32x4){0.f, 0.f, 0.f, 0.f};
                tap = __builtin_amdgcn_mfma_f32_16x16x32_bf16(afr[m][0], b0, tap, 0, 0, 0);
                tap = __builtin_amdgcn_mfma_f32_16x16x32_bf16(afr[m][1], b1, tap, 0, 0, 0);
                acc[m][nt] += tap * iv;
            }
        }
    }

    #pragma unroll
    for (int m = 0; m < 4; ++m) {
        #pragma unroll
        for (int nt = 0; nt < 4; ++nt) {
            const int rl = 2 * wv + (nt >> 1);
            const int gh = h0 + rl;
            const int gw = w0 + (nt & 1) * 16 + l15;
            #pragma unroll
            for (int r = 0; r < 4; ++r) {
                const int o = m * 16 + lg * 4 + r;
                const float v = wm * acc[m][nt][r] + bias_lds[o];
                out[(((size_t)n * XO + o) * XH + gh) * XW + gw] = v;
            }
        }
    }
}

extern "C" void kernel_launch(void* const* d_in, const int* in_sizes, int n_in,
                              void* d_out, int out_size, void* d_ws, size_t ws_size,
                              hipStream_t stream) {
    const float* x    = (const float*)d_in[0];
    const float* w    = (const float*)d_in[1];
    const float* bias = (const float*)d_in[2];
    float* out = (float*)d_out;

    if (ws_size >= (size_t)WS_NEED) {
        signed char* qx       = (signed char*)d_ws;
        float*       invsb    = (float*)((char*)d_ws + INVS_OFF);
        signed char* wbuf     = (signed char*)((char*)d_ws + WBUF_OFF);
        float*       partials = (float*)((char*)d_ws + PART_OFF);
        float*       wm       = (float*)((char*)d_ws + WM_OFF);

        wq_reduce<<<64, 256, 0, stream>>>(w, partials);
        wq_tern_i8<<<144, 256, 0, stream>>>(w, partials, wm, wbuf);
        aq_i8<<<XN * 256, 256, 0, stream>>>(x, qx, invsb);
        conv_i8<<<XN * 256, 256, 0, stream>>>(qx, invsb, wbuf, wm, bias, out);
    } else {
        float* wsf  = (float*)d_ws;
        u16*   wbuf = (u16*)((char*)d_ws + 64);
        wq_kernel<<<1, 256, 0, stream>>>(w, wsf, wbuf);
        conv_kernel<<<XN * 256, 256, 0, stream>>>(x, wbuf, wsf, bias, out);
    }
}